// Round 9
// baseline (651.955 us; speedup 1.0000x reference)
//
#include <hip/hip_runtime.h>
#include <math.h>

#define NB 8
#define NC 512
#define NH 24
#define NW 24
#define NL 576        // NH*NW
#define ND 1024       // D_INNER
#define NBL 4608      // NB*NL
#define NCH 8         // scan chunks
#define CL 72         // chunk length (NL/NCH)

static constexpr float SCALE_ = 0.044194173824159216f; // 1/sqrt(512)

typedef __attribute__((ext_vector_type(8))) short bf16x8;
typedef __attribute__((ext_vector_type(4))) float f32x4;

// ---------- order-preserving float<->uint encoding for atomicMax ----------
__device__ __forceinline__ unsigned enc_f(float f){
    unsigned u = __float_as_uint(f);
    return (u & 0x80000000u) ? ~u : (u | 0x80000000u);
}
__device__ __forceinline__ float dec_f(unsigned e){
    return (e & 0x80000000u) ? __uint_as_float(e ^ 0x80000000u) : __uint_as_float(~e);
}

// scan-position -> hw-index map for direction k
__device__ __forceinline__ int scan_idx(int t, int k){
    int t2 = (k >= 2) ? (NL - 1 - t) : t;
    return (k & 1) ? ((t2 % NH) * NW + t2 / NH) : t2;
}

// fast softplus / silu via v_exp/v_log
__device__ __forceinline__ float softplus_f(float x){
    return fmaxf(x, 0.f) + __logf(1.f + __expf(-fabsf(x)));
}
__device__ __forceinline__ float silu_f(float x){
    return x / (1.f + __expf(-x));
}

// fp32 -> bf16 hi/lo split (round-nearest-even both)
__device__ __forceinline__ void split_bf(float v, unsigned short &h, unsigned short &l){
    unsigned u = __float_as_uint(v);
    unsigned hr = (u + 0x7fffu + ((u>>16)&1u)) >> 16;
    h = (unsigned short)hr;
    float hf = __uint_as_float(hr << 16);
    unsigned u2 = __float_as_uint(v - hf);
    l = (unsigned short)((u2 + 0x7fffu + ((u2>>16)&1u)) >> 16);
}

// ---------- LDS-tiled transpose x5 (B,C,L) -> x5t (B,L,C) fp32 + B-form bf16 ----------
__global__ void k_transpose_in(const float* __restrict__ x5, float* __restrict__ x5t,
                               unsigned short* __restrict__ x5tB){
    __shared__ float t[32][33];
    const int b = blockIdx.z;
    const int c0 = blockIdx.x*32, l0 = blockIdx.y*32;
    const int tx = threadIdx.x & 31, ty = threadIdx.x >> 5;   // 32x8
    #pragma unroll
    for (int i=ty; i<32; i+=8)
        t[i][tx] = x5[((size_t)b*NC + c0 + i)*NL + l0 + tx];
    __syncthreads();
    #pragma unroll
    for (int i=ty; i<32; i+=8){
        float v = t[tx][i];
        x5t[((size_t)b*NL + l0 + i)*NC + c0 + tx] = v;
        unsigned short hh, ll; split_bf(v, hh, ll);
        size_t rb = ((size_t)b*NL + l0 + i)*1536 + c0 + tx;
        x5tB[rb] = hh; x5tB[rb+512] = ll; x5tB[rb+1024] = hh;
    }
}

// ---------- fp32 -> split-bf16 forms ----------
// A-form row layout (3K): [hi | hi | lo];  B-form: [hi | lo | hi]
template<int FORM>
__global__ void k_split(const float* __restrict__ in, unsigned short* __restrict__ oA,
                        unsigned short* __restrict__ oB, int K, int total4){
    int t = blockIdx.x*256 + threadIdx.x;
    if (t >= total4) return;
    int kq = K >> 2;
    int r = t / kq; int k4 = (t - r*kq) << 2;
    float4 v = *(const float4*)(in + (size_t)r*K + k4);
    float vv[4] = {v.x, v.y, v.z, v.w};
    unsigned short h[4], lo[4];
    #pragma unroll
    for (int i=0;i<4;i++) split_bf(vv[i], h[i], lo[i]);
    unsigned hp0 = h[0] | ((unsigned)h[1]<<16), hp1 = h[2] | ((unsigned)h[3]<<16);
    unsigned lp0 = lo[0] | ((unsigned)lo[1]<<16), lp1 = lo[2] | ((unsigned)lo[3]<<16);
    size_t base = (size_t)r*3*K + k4;
    if (FORM == 0 || FORM == 2){
        unsigned* p0 = (unsigned*)(oA + base);
        unsigned* p1 = (unsigned*)(oA + base + K);
        unsigned* p2 = (unsigned*)(oA + base + 2*K);
        p0[0]=hp0; p0[1]=hp1;  p1[0]=hp0; p1[1]=hp1;  p2[0]=lp0; p2[1]=lp1;
    }
    if (FORM == 1 || FORM == 2){
        unsigned short* o = (FORM==2) ? oB : oA;
        unsigned* p0 = (unsigned*)(o + base);
        unsigned* p1 = (unsigned*)(o + base + K);
        unsigned* p2 = (unsigned*)(o + base + 2*K);
        p0[0]=hp0; p0[1]=hp1;  p1[0]=lp0; p1[1]=lp1;  p2[0]=hp0; p2[1]=hp1;
    }
}

// ---------- MFMA bf16x3 NT GEMM, register-prefetch pipelined ----------
// MODE 0: conv1x1 (+bias+residual) | 1: in_proj split | 3: out_proj (+residual)
// MODE 4: gram, compact upper-tri 1D grid, row/col max -> mbuf
template<int MODE>
__launch_bounds__(256)
__global__ void mfma_nt(const unsigned short* __restrict__ A, const unsigned short* __restrict__ Bm,
                        const float* __restrict__ R0, const float* __restrict__ R1,
                        float* __restrict__ out0, float* __restrict__ out1,
                        unsigned* __restrict__ mbuf, int K3)
{
    int bi, bj;
    if (MODE == 4){
        int rem = blockIdx.x, len = 36; bi = 0;
        while (rem >= len){ rem -= len; len--; bi++; }
        bj = bi + rem;
    } else { bi = blockIdx.x; bj = blockIdx.y; }
    const int m0 = bi*128, n0 = bj*128;
    __shared__ __align__(16) unsigned short As[128*32];
    __shared__ __align__(16) unsigned short Bs[128*32];
    const int tid = threadIdx.x;
    const int w = tid >> 6, l = tid & 63;
    const int mw = (w>>1)*64, nw = (w&1)*64;
    const int fr = l & 15, fq = l >> 4;

    f32x4 acc[4][4];
    #pragma unroll
    for (int i=0;i<4;i++)
        #pragma unroll
        for (int j=0;j<4;j++)
            #pragma unroll
            for (int c=0;c<4;c++) acc[i][j][c] = 0.f;

    const int c0 = tid, c1 = tid + 256;
    const int r0 = c0 >> 2, o0 = (c0 & 3) * 8;
    const int r1 = c1 >> 2, o1 = (c1 & 3) * 8;
    const unsigned short* pA0 = A  + (size_t)(m0 + r0)*K3 + o0;
    const unsigned short* pA1 = A  + (size_t)(m0 + r1)*K3 + o1;
    const unsigned short* pB0 = Bm + (size_t)(n0 + r0)*K3 + o0;
    const unsigned short* pB1 = Bm + (size_t)(n0 + r1)*K3 + o1;

    float4 a0 = *(const float4*)(pA0);
    float4 a1 = *(const float4*)(pA1);
    float4 b0 = *(const float4*)(pB0);
    float4 b1 = *(const float4*)(pB1);

    for (int k0 = 0; k0 < K3; k0 += 32){
        __syncthreads();
        *(float4*)&As[c0*8] = a0;
        *(float4*)&As[c1*8] = a1;
        *(float4*)&Bs[c0*8] = b0;
        *(float4*)&Bs[c1*8] = b1;
        __syncthreads();
        if (k0 + 32 < K3){
            a0 = *(const float4*)(pA0 + k0 + 32);
            a1 = *(const float4*)(pA1 + k0 + 32);
            b0 = *(const float4*)(pB0 + k0 + 32);
            b1 = *(const float4*)(pB1 + k0 + 32);
        }
        bf16x8 af[4], bf[4];
        #pragma unroll
        for (int i=0;i<4;i++){
            af[i] = *(const bf16x8*)&As[(mw + i*16 + fr)*32 + fq*8];
            bf[i] = *(const bf16x8*)&Bs[(nw + i*16 + fr)*32 + fq*8];
        }
        #pragma unroll
        for (int i=0;i<4;i++)
            #pragma unroll
            for (int j=0;j<4;j++)
                acc[i][j] = __builtin_amdgcn_mfma_f32_16x16x32_bf16(af[i], bf[j], acc[i][j], 0, 0, 0);
    }

    if (MODE == 4){
        const int b2c = (n0 + nw) / NL;
        #pragma unroll
        for (int mi=0; mi<4; mi++){
            #pragma unroll
            for (int i=0;i<4;i++){
                float v = fmaxf(fmaxf(acc[mi][0][i], acc[mi][1][i]),
                                fmaxf(acc[mi][2][i], acc[mi][3][i]));
                v = fmaxf(v, __shfl_xor(v, 1));
                v = fmaxf(v, __shfl_xor(v, 2));
                v = fmaxf(v, __shfl_xor(v, 4));
                v = fmaxf(v, __shfl_xor(v, 8));
                if (fr == 0)
                    atomicMax(&mbuf[(size_t)(m0 + mw + mi*16 + fq*4 + i)*NB + b2c], enc_f(v));
            }
        }
        const int b2r = (m0 + mw) / NL;
        #pragma unroll
        for (int ni=0; ni<4; ni++){
            float cm = -3.4e38f;
            #pragma unroll
            for (int mi=0; mi<4; mi++)
                #pragma unroll
                for (int i=0;i<4;i++) cm = fmaxf(cm, acc[mi][ni][i]);
            cm = fmaxf(cm, __shfl_xor(cm, 16));
            cm = fmaxf(cm, __shfl_xor(cm, 32));
            if (fq == 0)
                atomicMax(&mbuf[(size_t)(n0 + nw + ni*16 + fr)*NB + b2r], enc_f(cm));
        }
        return;
    }

    #pragma unroll
    for (int mi=0; mi<4; mi++){
        const int m = m0 + mw + mi*16 + fq*4;
        #pragma unroll
        for (int ni=0; ni<4; ni++){
            const int n = n0 + nw + ni*16 + fr;
            f32x4 a = acc[mi][ni];
            if (MODE == 0){
                float4 cb = *(const float4*)(R0 + m);
                float4 rs = *(const float4*)(R1 + (size_t)n*NC + m);
                float4 ov = make_float4(a[0]+cb.x+rs.x, a[1]+cb.y+rs.y, a[2]+cb.z+rs.z, a[3]+cb.w+rs.w);
                *(float4*)(out0 + (size_t)n*NC + m) = ov;
            } else if (MODE == 1){
                float4 ov = make_float4(a[0], a[1], a[2], a[3]);
                if (m < ND) *(float4*)(out0 + (size_t)n*ND + m) = ov;
                else        *(float4*)(out1 + (size_t)n*ND + (m - ND)) = ov;
            } else { // MODE 3
                float4 rs = *(const float4*)(R1 + (size_t)n*NC + m);
                float4 ov = make_float4(a[0]+rs.x, a[1]+rs.y, a[2]+rs.z, a[3]+rs.w);
                *(float4*)(out0 + (size_t)n*NC + m) = ov;
            }
        }
    }
}

// ---------- fp32 NT tiled GEMM (x_proj only, MODE 2) ----------
template<int MODE>
__launch_bounds__(256)
__global__ void gemm_nt(const float* __restrict__ A0, const float* __restrict__ B0,
                        const float* __restrict__ R,
                        float* __restrict__ out0, float* __restrict__ out1,
                        unsigned* __restrict__ mbuf, int K)
{
    __shared__ __align__(16) float As[16][68];
    __shared__ __align__(16) float Bs[16][68];
    const int tid = threadIdx.x;
    const int m0 = blockIdx.x * 64;
    const int n0 = blockIdx.y * 64;
    const float* A = A0;
    const float* B = B0;
    int kdir = 0;
    if (MODE == 2) {
        const int bk = blockIdx.z;         // b*4 + k
        kdir = bk & 3; const int bb = bk >> 2;
        A = A0 + (size_t)kdir * 64 * 1024;
        B = B0 + (size_t)bb * NL * 1024;
    }
    const int lrow = tid >> 2;
    const int lk4  = (tid & 3) << 2;
    int brow = n0 + lrow;
    if (MODE == 2) brow = scan_idx(brow, kdir);
    const float* aptr = A + (size_t)(m0 + lrow) * K + lk4;
    const float* bptr = B + (size_t)brow * K + lk4;

    float acc[4][4];
    #pragma unroll
    for (int i=0;i<4;i++){
        #pragma unroll
        for (int j=0;j<4;j++) acc[i][j]=0.f;
    }
    const int tx = tid & 15, ty = tid >> 4;

    for (int k0 = 0; k0 < K; k0 += 16) {
        float4 av = *(const float4*)(aptr + k0);
        float4 bv = *(const float4*)(bptr + k0);
        __syncthreads();
        As[lk4+0][lrow]=av.x; As[lk4+1][lrow]=av.y; As[lk4+2][lrow]=av.z; As[lk4+3][lrow]=av.w;
        Bs[lk4+0][lrow]=bv.x; Bs[lk4+1][lrow]=bv.y; Bs[lk4+2][lrow]=bv.z; Bs[lk4+3][lrow]=bv.w;
        __syncthreads();
        #pragma unroll
        for (int kk=0;kk<16;kk++){
            float4 a = *(const float4*)&As[kk][ty<<2];
            float4 b = *(const float4*)&Bs[kk][tx<<2];
            acc[0][0] = fmaf(a.x,b.x,acc[0][0]); acc[0][1] = fmaf(a.x,b.y,acc[0][1]);
            acc[0][2] = fmaf(a.x,b.z,acc[0][2]); acc[0][3] = fmaf(a.x,b.w,acc[0][3]);
            acc[1][0] = fmaf(a.y,b.x,acc[1][0]); acc[1][1] = fmaf(a.y,b.y,acc[1][1]);
            acc[1][2] = fmaf(a.y,b.z,acc[1][2]); acc[1][3] = fmaf(a.y,b.w,acc[1][3]);
            acc[2][0] = fmaf(a.z,b.x,acc[2][0]); acc[2][1] = fmaf(a.z,b.y,acc[2][1]);
            acc[2][2] = fmaf(a.z,b.z,acc[2][2]); acc[2][3] = fmaf(a.z,b.w,acc[2][3]);
            acc[3][0] = fmaf(a.w,b.x,acc[3][0]); acc[3][1] = fmaf(a.w,b.y,acc[3][1]);
            acc[3][2] = fmaf(a.w,b.z,acc[3][2]); acc[3][3] = fmaf(a.w,b.w,acc[3][3]);
        }
    }

    #pragma unroll
    for (int j=0;j<4;j++){
        const int n  = n0 + (tx<<2) + j;
        const int mm = m0 + (ty<<2);
        float4 v = make_float4(acc[0][j], acc[1][j], acc[2][j], acc[3][j]);
        if (MODE == 2){
            *(float4*)(out0 + ((size_t)blockIdx.z*NL + n)*64 + mm) = v;
        }
    }
}

// ---------- layernorm over C=512, directly to B-form bf16x3 ----------
__global__ void k_ln512b(const float* __restrict__ x, const float* __restrict__ g,
                         const float* __restrict__ bb, unsigned short* __restrict__ outB){
    int n = blockIdx.x; int tid = threadIdx.x;     // 256 threads
    const float* row = x + (size_t)n*NC;
    float v0 = row[tid], v1 = row[tid+256];
    __shared__ float s1[256], s2[256];
    s1[tid] = v0+v1; s2[tid] = v0*v0 + v1*v1;
    __syncthreads();
    for (int s=128;s>0;s>>=1){ if (tid<s){ s1[tid]+=s1[tid+s]; s2[tid]+=s2[tid+s]; } __syncthreads(); }
    float mean = s1[0]*(1.f/NC);
    float var  = fmaxf(s2[0]*(1.f/NC) - mean*mean, 0.f);
    float rs   = rsqrtf(var + 1e-5f);
    float r0 = (v0-mean)*rs*g[tid]     + bb[tid];
    float r1 = (v1-mean)*rs*g[tid+256] + bb[tid+256];
    unsigned short h0,l0,h1,l1; split_bf(r0,h0,l0); split_bf(r1,h1,l1);
    size_t base = (size_t)n*1536;
    outB[base+tid]     =h0; outB[base+512+tid]     =l0; outB[base+1024+tid]     =h0;
    outB[base+tid+256] =h1; outB[base+512+tid+256] =l1; outB[base+1024+tid+256] =h1;
}

// ---------- depthwise 3x3 SAME + bias + SiLU, rolling window ----------
__global__ void k_dwconv(const float* __restrict__ xi, const float* __restrict__ w,
                         const float* __restrict__ bias, float* __restrict__ xcl){
    int d = blockIdx.x*256 + threadIdx.x;          // 0..1023
    int h = blockIdx.y; int b = blockIdx.z;
    float W[9];
    #pragma unroll
    for (int i=0;i<9;i++) W[i] = w[d*9+i];
    float bs = bias[d];
    const size_t rb = ((size_t)b*NL)*ND + d;
    const bool hm = h > 0, hp = h < NH-1;
    float p0=0.f,p1=0.f,p2=0.f;
    float c0 = hm ? xi[rb + (size_t)((h-1)*NW)*ND] : 0.f;
    float c1 = xi[rb + (size_t)(h*NW)*ND];
    float c2 = hp ? xi[rb + (size_t)((h+1)*NW)*ND] : 0.f;
    for (int wc=0; wc<NW; wc++){
        float n0,n1,n2;
        if (wc < NW-1){
            n0 = hm ? xi[rb + (size_t)((h-1)*NW+wc+1)*ND] : 0.f;
            n1 = xi[rb + (size_t)(h*NW+wc+1)*ND];
            n2 = hp ? xi[rb + (size_t)((h+1)*NW+wc+1)*ND] : 0.f;
        } else { n0=0.f;n1=0.f;n2=0.f; }
        float acc = bs;
        acc = fmaf(W[0],p0, fmaf(W[1],c0, fmaf(W[2],n0, acc)));
        acc = fmaf(W[3],p1, fmaf(W[4],c1, fmaf(W[5],n1, acc)));
        acc = fmaf(W[6],p2, fmaf(W[7],c2, fmaf(W[8],n2, acc)));
        xcl[rb + (size_t)(h*NW+wc)*ND] = silu_f(acc);
        p0=c0;p1=c1;p2=c2; c0=n0;c1=n1;c2=n2;
    }
}

// dA power tree from e1
#define DA_POWERS \
    float e2=e1*e1; float e3=e2*e1; float e4=e2*e2; \
    float e6=e4*e2; float e7=e4*e3; float e8=e4*e4; float e12=e8*e4; \
    float dA[16]; \
    dA[0]=e1; dA[1]=e2; dA[2]=e3; dA[3]=e4; dA[4]=e4*e1; dA[5]=e6; dA[6]=e7; dA[7]=e8; \
    dA[8]=e8*e1; dA[9]=e8*e2; dA[10]=e8*e3; dA[11]=e12; dA[12]=e12*e1; dA[13]=e12*e2; \
    dA[14]=e12*e3; dA[15]=e8*e8;

// 4-chain dot of row (float4s q0..q7) with wdt[32]
#define DOT4(rq, dtb, out) { \
    float4 q0=rq[0],q1=rq[1],q2=rq[2],q3=rq[3],q4=rq[4],q5=rq[5],q6=rq[6],q7=rq[7]; \
    float s0=0.f,s1=0.f,s2=0.f,s3=0.f; \
    s0=fmaf(q0.x,wdt[0],s0);  s1=fmaf(q0.y,wdt[1],s1);  s2=fmaf(q0.z,wdt[2],s2);  s3=fmaf(q0.w,wdt[3],s3); \
    s0=fmaf(q1.x,wdt[4],s0);  s1=fmaf(q1.y,wdt[5],s1);  s2=fmaf(q1.z,wdt[6],s2);  s3=fmaf(q1.w,wdt[7],s3); \
    s0=fmaf(q2.x,wdt[8],s0);  s1=fmaf(q2.y,wdt[9],s1);  s2=fmaf(q2.z,wdt[10],s2); s3=fmaf(q2.w,wdt[11],s3); \
    s0=fmaf(q3.x,wdt[12],s0); s1=fmaf(q3.y,wdt[13],s1); s2=fmaf(q3.z,wdt[14],s2); s3=fmaf(q3.w,wdt[15],s3); \
    s0=fmaf(q4.x,wdt[16],s0); s1=fmaf(q4.y,wdt[17],s1); s2=fmaf(q4.z,wdt[18],s2); s3=fmaf(q4.w,wdt[19],s3); \
    s0=fmaf(q5.x,wdt[20],s0); s1=fmaf(q5.y,wdt[21],s1); s2=fmaf(q5.z,wdt[22],s2); s3=fmaf(q5.w,wdt[23],s3); \
    s0=fmaf(q6.x,wdt[24],s0); s1=fmaf(q6.y,wdt[25],s1); s2=fmaf(q6.z,wdt[26],s2); s3=fmaf(q6.w,wdt[27],s3); \
    s0=fmaf(q7.x,wdt[28],s0); s1=fmaf(q7.y,wdt[29],s1); s2=fmaf(q7.z,wdt[30],s2); s3=fmaf(q7.w,wdt[31],s3); \
    out = (s0+s1)+(s2+s3)+dtb; }

// ---------- chunked selective scan, pass 1 (128 threads) ----------
__launch_bounds__(128)
__global__ void k_scan_p1(const float* __restrict__ xcl, const float* __restrict__ xdbl,
                          const float* __restrict__ dtw, const float* __restrict__ dtb,
                          const float* __restrict__ alogs,
                          float* __restrict__ hfin, float* __restrict__ prodA){
    const int d = blockIdx.x*128 + threadIdx.x;
    const int chunk = blockIdx.y;
    const int bk = blockIdx.z;
    const int k = bk & 3, b = bk >> 2;
    const int kd = k*ND + d;
    float wdt[32];
    {
        const float4* p = (const float4*)(dtw + (size_t)kd*32);
        #pragma unroll
        for (int i=0;i<8;i++){ float4 v=p[i]; wdt[4*i]=v.x; wdt[4*i+1]=v.y; wdt[4*i+2]=v.z; wdt[4*i+3]=v.w; }
    }
    float An[16]; bool ladder = true;
    {
        const float4* p = (const float4*)(alogs + (size_t)kd*16);
        #pragma unroll
        for (int i=0;i<4;i++){
            float4 v=p[i];
            An[4*i]=-__expf(v.x); An[4*i+1]=-__expf(v.y); An[4*i+2]=-__expf(v.z); An[4*i+3]=-__expf(v.w);
        }
        #pragma unroll
        for (int n=0;n<16;n++) ladder = ladder && (fabsf(An[n] + (float)(n+1)) < 1e-3f*(n+1));
    }
    const float dtbias = dtb[kd];
    __shared__ __align__(16) float rows[CL*64];
    {
        const float4* src = (const float4*)(xdbl + ((size_t)bk*NL + chunk*CL)*64);
        for (int i = threadIdx.x; i < CL*16; i += 128) ((float4*)rows)[i] = src[i];
    }
    __syncthreads();
    float h[16], pA[16];
    #pragma unroll
    for (int n=0;n<16;n++){ h[n]=0.f; pA[n]=1.f; }
    if (ladder){
        float u = xcl[((size_t)b*NL + scan_idx(chunk*CL, k))*ND + d];
        for (int t=0;t<CL;t++){
            const float4* rq = (const float4*)(rows + t*64);
            float dr; DOT4(rq, dtbias, dr);
            float u_cur = u;
            if (t+1 < CL) u = xcl[((size_t)b*NL + scan_idx(chunk*CL+t+1, k))*ND + d];
            float sp = softplus_f(dr);
            float du = sp * u_cur;
            float e1 = __expf(-sp);
            DA_POWERS
            float4 B0=rq[8],B1=rq[9],B2=rq[10],B3=rq[11];
            const float Bv[16] = {B0.x,B0.y,B0.z,B0.w,B1.x,B1.y,B1.z,B1.w,
                                  B2.x,B2.y,B2.z,B2.w,B3.x,B3.y,B3.z,B3.w};
            #pragma unroll
            for (int n=0;n<16;n++){
                pA[n] *= dA[n];
                h[n] = fmaf(dA[n], h[n], du*Bv[n]);
            }
        }
    } else {
        for (int t=0;t<CL;t++){
            const float4* rq = (const float4*)(rows + t*64);
            float dr; DOT4(rq, dtbias, dr);
            float sp = softplus_f(dr);
            int idx = scan_idx(chunk*CL + t, k);
            float u  = xcl[((size_t)b*NL + idx)*ND + d];
            float du = sp * u;
            const float* row = rows + t*64;
            #pragma unroll
            for (int n=0;n<16;n++){
                float dA = __expf(sp * An[n]);
                pA[n] *= dA;
                h[n] = fmaf(dA, h[n], du*row[32+n]);
            }
        }
    }
    size_t base = (size_t)(bk*NCH + chunk)*16*1024 + d;
    #pragma unroll
    for (int n=0;n<16;n++){ hfin[base + n*1024] = h[n]; prodA[base + n*1024] = pA[n]; }
}

// ---------- chunked scan, mid ----------
__global__ void k_scan_mid(float* __restrict__ hfin, const float* __restrict__ prodA){
    int id = blockIdx.x*256 + threadIdx.x;
    int d = id & 1023, nn = (id >> 10) & 15, bk = id >> 14;
    float h = 0.f;
    for (int j=0;j<NCH;j++){
        size_t idx = (size_t)((bk*NCH + j)*16 + nn)*1024 + d;
        float hf = hfin[idx], pa = prodA[idx];
        hfin[idx] = h;
        h = fmaf(pa, h, hf);
    }
}

// ---------- chunked scan, pass 2 (128 threads) ----------
__launch_bounds__(128)
__global__ void k_scan_p2(const float* __restrict__ xcl, const float* __restrict__ xdbl,
                          const float* __restrict__ dtw, const float* __restrict__ dtb,
                          const float* __restrict__ alogs,
                          const float* __restrict__ hfin, float* __restrict__ yacc){
    const int d = blockIdx.x*128 + threadIdx.x;
    const int chunk = blockIdx.y;
    const int bk = blockIdx.z;
    const int k = bk & 3, b = bk >> 2;
    const int kd = k*ND + d;
    float wdt[32];
    {
        const float4* p = (const float4*)(dtw + (size_t)kd*32);
        #pragma unroll
        for (int i=0;i<8;i++){ float4 v=p[i]; wdt[4*i]=v.x; wdt[4*i+1]=v.y; wdt[4*i+2]=v.z; wdt[4*i+3]=v.w; }
    }
    float An[16]; bool ladder = true;
    {
        const float4* p = (const float4*)(alogs + (size_t)kd*16);
        #pragma unroll
        for (int i=0;i<4;i++){
            float4 v=p[i];
            An[4*i]=-__expf(v.x); An[4*i+1]=-__expf(v.y); An[4*i+2]=-__expf(v.z); An[4*i+3]=-__expf(v.w);
        }
        #pragma unroll
        for (int n=0;n<16;n++) ladder = ladder && (fabsf(An[n] + (float)(n+1)) < 1e-3f*(n+1));
    }
    const float dtbias = dtb[kd];
    __shared__ __align__(16) float rows[CL*64];
    {
        const float4* src = (const float4*)(xdbl + ((size_t)bk*NL + chunk*CL)*64);
        for (int i = threadIdx.x; i < CL*16; i += 128) ((float4*)rows)[i] = src[i];
    }
    __syncthreads();
    float h[16];
    {
        size_t base = (size_t)(bk*NCH + chunk)*16*1024 + d;
        #pragma unroll
        for (int n=0;n<16;n++) h[n] = hfin[base + n*1024];
    }
    if (ladder){
        int idx = scan_idx(chunk*CL, k);
        float u = xcl[((size_t)b*NL + idx)*ND + d];
        for (int t=0;t<CL;t++){
            const float4* rq = (const float4*)(rows + t*64);
            float dr; DOT4(rq, dtbias, dr);
            float u_cur = u; int idx_cur = idx;
            if (t+1 < CL){
                idx = scan_idx(chunk*CL+t+1, k);
                u = xcl[((size_t)b*NL + idx)*ND + d];
            }
            float sp = softplus_f(dr);
            float du = sp * u_cur;
            float e1 = __expf(-sp);
            DA_POWERS
            float4 B0=rq[8],B1=rq[9],B2=rq[10],B3=rq[11];
            float4 C0=rq[12],C1=rq[13],C2=rq[14],C3=rq[15];
            const float Bv[16] = {B0.x,B0.y,B0.z,B0.w,B1.x,B1.y,B1.z,B1.w,
                                  B2.x,B2.y,B2.z,B2.w,B3.x,B3.y,B3.z,B3.w};
            const float Cv[16] = {C0.x,C0.y,C0.z,C0.w,C1.x,C1.y,C1.z,C1.w,
                                  C2.x,C2.y,C2.z,C2.w,C3.x,C3.y,C3.z,C3.w};
            float y0=0.f, y1=0.f;
            #pragma unroll
            for (int n=0;n<16;n++){
                h[n] = fmaf(dA[n], h[n], du*Bv[n]);
                if (n & 1) y1 = fmaf(h[n], Cv[n], y1); else y0 = fmaf(h[n], Cv[n], y0);
            }
            atomicAdd(&yacc[((size_t)b*NL + idx_cur)*ND + d], y0+y1);
        }
    } else {
        for (int t=0;t<CL;t++){
            const float4* rq = (const float4*)(rows + t*64);
            float dr; DOT4(rq, dtbias, dr);
            float sp = softplus_f(dr);
            int idx = scan_idx(chunk*CL + t, k);
            size_t base = ((size_t)b*NL + idx)*ND + d;
            float u  = xcl[base];
            float du = sp * u;
            const float* row = rows + t*64;
            float y = 0.f;
            #pragma unroll
            for (int n=0;n<16;n++){
                float dA = __expf(sp * An[n]);
                h[n] = fmaf(dA, h[n], du*row[32+n]);
                y = fmaf(h[n], row[48+n], y);
            }
            atomicAdd(&yacc[base], y);
        }
    }
}

// ---------- combine y + Ds*u, LN over D, gate with silu(z) -> zB (B-form bf16x3) ----------
__global__ void k_combine(const float* __restrict__ y, const float* __restrict__ xcl,
                          const float* __restrict__ Ds,
                          const float* __restrict__ g, const float* __restrict__ bb,
                          const float* __restrict__ z, unsigned short* __restrict__ zB){
    int n = blockIdx.x;
    size_t base = (size_t)n*ND;
    int tid = threadIdx.x;
    float v[4]; float sum=0.f, sq=0.f;
    #pragma unroll
    for (int j=0;j<4;j++){
        int d = tid + 256*j;
        float ds = Ds[d] + Ds[ND+d] + Ds[2*ND+d] + Ds[3*ND+d];
        float val = y[base+d] + ds*xcl[base+d];
        v[j]=val; sum+=val; sq+=val*val;
    }
    __shared__ float s1[256], s2[256];
    s1[tid]=sum; s2[tid]=sq; __syncthreads();
    for (int st=128;st>0;st>>=1){ if(tid<st){ s1[tid]+=s1[tid+st]; s2[tid]+=s2[tid+st]; } __syncthreads(); }
    float mean = s1[0]*(1.f/ND);
    float var  = fmaxf(s2[0]*(1.f/ND) - mean*mean, 0.f);
    float rs   = rsqrtf(var + 1e-5f);
    size_t zb = (size_t)n*3072;
    #pragma unroll
    for (int j=0;j<4;j++){
        int d = tid + 256*j;
        float ln = (v[j]-mean)*rs*g[d] + bb[d];
        float res = ln * silu_f(z[base+d]);
        unsigned short hh,ll; split_bf(res,hh,ll);
        zB[zb + d] = hh; zB[zb + 1024 + d] = ll; zB[zb + 2048 + d] = hh;
    }
}

// ---------- xw_pre = SCALE/8 * sum_b2 max ----------
__global__ void k_xwpre(const unsigned* __restrict__ M, float* __restrict__ xwp){
    int n = blockIdx.x*256 + threadIdx.x; if (n >= NBL) return;
    float sum = 0.f;
    #pragma unroll
    for (int b2=0;b2<NB;b2++) sum += dec_f(M[(size_t)n*NB + b2]);
    xwp[n] = sum * (SCALE_/8.f);
}

// ---------- per-b argmax mask ----------
__global__ void k_mask(const float* __restrict__ xwp, float* __restrict__ maskf){
    int b = blockIdx.x; int tid = threadIdx.x;     // 64 threads
    float m = -1e30f;
    for (int i=tid;i<NL;i+=64) m = fmaxf(m, xwp[b*NL+i]);
    __shared__ float s1[64];
    s1[tid]=m; __syncthreads();
    for (int st=32;st>0;st>>=1){ if(tid<st) s1[tid]=fmaxf(s1[tid],s1[tid+st]); __syncthreads(); }
    float bm = s1[0];
    for (int i=tid;i<NL;i+=64) maskf[b*NL+i] = (xwp[b*NL+i]==bm) ? 1.f : 0.f;
}

// ---------- channel-norm: norm0 (B,L,C) ----------
__global__ void k_norm0(const float* __restrict__ x5r, float* __restrict__ norm0){
    int n = blockIdx.x; int tid = threadIdx.x;     // 256
    float v0 = x5r[(size_t)n*NC+tid], v1 = x5r[(size_t)n*NC+tid+256];
    __shared__ float s1[256];
    s1[tid] = v0*v0 + v1*v1; __syncthreads();
    for (int st=128;st>0;st>>=1){ if(tid<st) s1[tid]+=s1[tid+st]; __syncthreads(); }
    float inv = 1.f / fmaxf(sqrtf(s1[0]), 1e-12f);
    norm0[(size_t)n*NC+tid]     = v0*inv;
    norm0[(size_t)n*NC+tid+256] = v1*inv;
}

// ---------- seeds[b,c] = sum_l norm0*mask ----------
__global__ void k_seeds(const float* __restrict__ norm0, const float* __restrict__ maskf,
                        float* __restrict__ seeds){
    int b = blockIdx.x; int c = threadIdx.x;       // 512
    float acc = 0.f;
    for (int l=0;l<NL;l++){
        float mk = maskf[b*NL+l];
        if (mk != 0.f) acc += norm0[((size_t)b*NL+l)*NC + c]*mk;
    }
    seeds[b*NC + c] = acc;
}

// ---------- cor[b,l] = mean_o relu(norm0 . seeds_o), wave-per-o ----------
__global__ void k_cor(const float* __restrict__ norm0, const float* __restrict__ seeds,
                      float* __restrict__ cor){
    int n = blockIdx.x; int tid = threadIdx.x;     // 512 = 8 waves
    int o = tid >> 6, lane = tid & 63;
    float acc = 0.f;
    #pragma unroll
    for (int i=0;i<8;i++){
        int c = lane + 64*i;
        acc += norm0[(size_t)n*NC + c] * seeds[o*NC + c];
    }
    #pragma unroll
    for (int s=32;s>0;s>>=1) acc += __shfl_xor(acc, s);
    __shared__ float sr[8];
    if (lane == 0) sr[o] = fmaxf(acc, 0.f);
    __syncthreads();
    if (tid == 0){
        float r = 0.f;
        #pragma unroll
        for (int o2=0;o2<8;o2++) r += sr[o2];
        cor[n] = r * (1.f/8.f);
    }
}

// ---------- cormap per b ----------
__global__ void k_cormap(const float* __restrict__ cor, float* __restrict__ cmap){
    int b = blockIdx.x, tid = threadIdx.x;         // 64
    float mn = 1e30f, mx = -1e30f;
    for (int i=tid;i<NL;i+=64){ float v=cor[b*NL+i]; mn=fminf(mn,v); mx=fmaxf(mx,v); }
    __shared__ float sn[64], sx[64];
    sn[tid]=mn; sx[tid]=mx; __syncthreads();
    for (int st=32;st>0;st>>=1){ if(tid<st){ sn[tid]=fminf(sn[tid],sn[tid+st]); sx[tid]=fmaxf(sx[tid],sx[tid+st]); } __syncthreads(); }
    float MN=sn[0], MX=sx[0];
    float inv = 1.f/(MX-MN+1e-12f);
    for (int i=tid;i<NL;i+=64) cmap[b*NL+i] = (cor[b*NL+i]-MN)*inv;
}

// ---------- proto accumulation ----------
__global__ void k_proto(const float* __restrict__ x5r, const float* __restrict__ cmap,
                        float* __restrict__ pacc){
    int c = threadIdx.x;                            // 512
    int chunk = blockIdx.x;                         // 72 chunks of 64
    float acc = 0.f;
    for (int i=0;i<64;i++){
        int n = chunk*64 + i;
        acc += x5r[(size_t)n*NC + c] * cmap[n];
    }
    atomicAdd(&pacc[c], acc);
}

// ---------- final outputs ----------
__global__ void k_final(const float* __restrict__ x5r, const float* __restrict__ cmap,
                        const float* __restrict__ pacc, const float* __restrict__ maskf,
                        float* __restrict__ out){
    int id = blockIdx.x*256 + threadIdx.x;          // over (b,c,l) = 2359296
    int l = id % NL; int bc = id / NL; int c = bc & 511; int b = bc >> 9;
    float v  = x5r[((size_t)b*NL + l)*NC + c];
    float p  = pacc[c] * (1.f/(float)NBL);
    float cm = cmap[b*NL + l];
    out[id] = v;                                    // output 0: x5
    out[2359296 + 512 + id] = v*(p + cm);           // output 2: x5*proto1 + x51
    if (id < 512)  out[2359296 + id] = pacc[id] * (1.f/(float)NBL);       // output 1
    if (id < NBL)  out[2359296 + 512 + 2359296 + id] = maskf[id];         // output 3
}

// ---------------- launcher ----------------
extern "C" void kernel_launch(void* const* d_in, const int* in_sizes, int n_in,
                              void* d_out, int out_size, void* d_ws, size_t ws_size,
                              hipStream_t stream) {
    const float* x5        = (const float*)d_in[0];
    const float* conv_w    = (const float*)d_in[1];
    const float* conv_b    = (const float*)d_in[2];
    const float* ln1_g     = (const float*)d_in[3];
    const float* ln1_b     = (const float*)d_in[4];
    const float* in_proj_w = (const float*)d_in[5];
    const float* dwconv_w  = (const float*)d_in[6];
    const float* dwconv_b  = (const float*)d_in[7];
    const float* x_proj_w  = (const float*)d_in[8];
    const float* dt_proj_w = (const float*)d_in[9];
    const float* dt_proj_b = (const float*)d_in[10];
    const float* A_logs    = (const float*)d_in[11];
    const float* Ds        = (const float*)d_in[12];
    const float* out_norm_g= (const float*)d_in[13];
    const float* out_norm_b= (const float*)d_in[14];
    const float* out_proj_w= (const float*)d_in[15];

    float* ws = (float*)d_ws;
    const size_t O_X5R  = 0;          // x5r (permanent)
    const size_t O_XLN  = 2359296;    // xqf
    const size_t O_XI   = 4718592;    // xi -> yacc -> wAo
    const size_t O_Z    = 9437184;    // z
    const size_t O_XCL  = 14155776;   // wAi -> xcl -> nrm0
    const size_t O_XDBL = 18874368;   // xdbl
    const size_t O_HF   = 20054016;   // x5t -> xlnB -> hfin -> zB(span) -> xqfA
    const size_t O_PA   = 24248320;   // x5tB+wAc -> prodA -> zB(tail) -> xqfB
    const size_t O_MBUF = 28442624;
    const size_t O_XWP  = 28479488;
    const size_t O_MASK = 28484096;
    const size_t O_COR  = 28488704;
    const size_t O_CMAP = 28493312;
    const size_t O_SEED = 28497920;
    const size_t O_PACC = 28502016;

    float* x5r  = ws + O_X5R;
    float* xqf  = ws + O_XLN;
    float* xi   = ws + O_XI;
    float* yacc = ws + O_XI;
    unsigned short* wAo = (unsigned short*)(ws + O_XI);
    float* z    = ws + O_Z;
    float* xcl  = ws + O_XCL;
    unsigned short* wAi = (unsigned short*)(ws + O_XCL);
    float* nrm0 = ws + O_XCL;
    float* xdbl = ws + O_XDBL;
    float* x5t  = ws + O_HF;
    float* hfin = ws + O_HF;
    unsigned short* xlnB = (unsigned short*)(ws + O_HF);
    unsigned short* zB   = (unsigned short*)(ws + O_HF);
    unsigned short* xqfA = (unsigned short*)(ws + O_HF);
    float* prodA = ws + O_PA;
    unsigned short* x5tB = (unsigned short*)(ws + O_PA);
    unsigned short* wAc  = (unsigned short*)(ws + O_PA) + 7077888;
    unsigned short* xqfB = (unsigned short*)(ws + O_PA);
    unsigned* mbuf = (unsigned*)(ws + O_MBUF);
    float* xwp  = ws + O_XWP;
    float* maskf= ws + O_MASK;
    float* cor  = ws + O_COR;
    float* cmap = ws + O_CMAP;
    float* seeds= ws + O_SEED;
    float* pacc = ws + O_PACC;

    (void)hipMemsetAsync(mbuf, 0, 36864*sizeof(unsigned), stream);
    (void)hipMemsetAsync(pacc, 0, 512*sizeof(float), stream);

    // 1. transpose x5 -> x5t (fp32) + x5tB (B-form bf16x3)
    k_transpose_in<<<dim3(16,18,8), 256, 0, stream>>>(x5, x5t, x5tB);
    // 2. conv1x1 via bf16x3 MFMA
    k_split<0><<<256, 256, 0, stream>>>(conv_w, wAc, nullptr, 512, 65536);
    mfma_nt<0><<<dim3(4,36), 256, 0, stream>>>(wAc, x5tB, conv_b, x5t, x5r, nullptr, nullptr, 1536);
    // 3. layernorm -> xlnB (B-form, overwrites x5t region — dead)
    k_ln512b<<<NBL, 256, 0, stream>>>(x5r, ln1_g, ln1_b, xlnB);
    // 4. in_proj via MFMA
    k_split<0><<<1024, 256, 0, stream>>>(in_proj_w, wAi, nullptr, 512, 262144);
    mfma_nt<1><<<dim3(16,36), 256, 0, stream>>>(wAi, xlnB, nullptr, nullptr, xi, z, nullptr, 1536);
    // 5. depthwise conv + silu
    k_dwconv<<<dim3(4,NH,NB), 256, 0, stream>>>(xi, dwconv_w, dwconv_b, xcl);
    // 6. zero y accumulator (xi dead)
    (void)hipMemsetAsync(yacc, 0, (size_t)4718592*sizeof(float), stream);
    // 7. x_proj (fp32, small)
    gemm_nt<2><<<dim3(1,9,32), 256, 0, stream>>>(x_proj_w, xcl, nullptr, xdbl, nullptr, nullptr, 1024);
    // 8. chunked selective scan (128-thread blocks)
    k_scan_p1<<<dim3(8,NCH,32), 128, 0, stream>>>(xcl, xdbl, dt_proj_w, dt_proj_b, A_logs, hfin, prodA);
    k_scan_mid<<<2048, 256, 0, stream>>>(hfin, prodA);
    k_scan_p2<<<dim3(8,NCH,32), 128, 0, stream>>>(xcl, xdbl, dt_proj_w, dt_proj_b, A_logs, hfin, yacc);
    // 9. combine + out-LN + gate -> zB directly (hfin/prodA dead)
    k_combine<<<NBL, 256, 0, stream>>>(yacc, xcl, Ds, out_norm_g, out_norm_b, z, zB);
    // 10. out_proj via MFMA (wAo in yacc region — dead)
    k_split<0><<<512, 256, 0, stream>>>(out_proj_w, wAo, nullptr, 1024, 131072);
    mfma_nt<3><<<dim3(4,36), 256, 0, stream>>>(wAo, zB, nullptr, x5r, xqf, nullptr, nullptr, 3072);
    // 11. Gram via MFMA, compact upper-tri grid (666 blocks)
    k_split<2><<<2304, 256, 0, stream>>>(xqf, xqfA, xqfB, 512, 589824);
    mfma_nt<4><<<666, 256, 0, stream>>>(xqfA, xqfB, nullptr, nullptr, nullptr, nullptr, mbuf, 1536);
    // 12. attention scalar pipeline
    k_xwpre<<<18, 256, 0, stream>>>(mbuf, xwp);
    k_mask<<<NB, 64, 0, stream>>>(xwp, maskf);
    k_norm0<<<NBL, 256, 0, stream>>>(x5r, nrm0);
    k_seeds<<<NB, 512, 0, stream>>>(nrm0, maskf, seeds);
    k_cor<<<NBL, 512, 0, stream>>>(nrm0, seeds, cor);
    k_cormap<<<NB, 64, 0, stream>>>(cor, cmap);
    k_proto<<<72, 512, 0, stream>>>(x5r, cmap, pacc);
    // 13. outputs
    k_final<<<9216, 256, 0, stream>>>(x5r, cmap, pacc, maskf, (float*)d_out);
}

// Round 10
// 616.783 us; speedup vs baseline: 1.0570x; 1.0570x over previous
//
#include <hip/hip_runtime.h>
#include <math.h>

#define NB 8
#define NC 512
#define NH 24
#define NW 24
#define NL 576        // NH*NW
#define ND 1024       // D_INNER
#define NBL 4608      // NB*NL
#define NCH 8         // scan chunks
#define CL 72         // chunk length (NL/NCH)

typedef __attribute__((ext_vector_type(8))) short bf16x8;
typedef __attribute__((ext_vector_type(4))) float f32x4;
typedef __attribute__((ext_vector_type(2))) float f32x2;

// ---------- order-preserving float<->uint encoding for atomicMax ----------
__device__ __forceinline__ unsigned enc_f(float f){
    unsigned u = __float_as_uint(f);
    return (u & 0x80000000u) ? ~u : (u | 0x80000000u);
}
__device__ __forceinline__ float dec_f(unsigned e){
    return (e & 0x80000000u) ? __uint_as_float(e ^ 0x80000000u) : __uint_as_float(~e);
}

// scan-position -> hw-index map for direction k
__device__ __forceinline__ int scan_idx(int t, int k){
    int t2 = (k >= 2) ? (NL - 1 - t) : t;
    return (k & 1) ? ((t2 % NH) * NW + t2 / NH) : t2;
}

// fast softplus / silu via v_exp/v_log
__device__ __forceinline__ float softplus_f(float x){
    return fmaxf(x, 0.f) + __logf(1.f + __expf(-fabsf(x)));
}
__device__ __forceinline__ float silu_f(float x){
    return x / (1.f + __expf(-x));
}

// fp32 -> bf16 hi/lo split (round-nearest-even both)
__device__ __forceinline__ void split_bf(float v, unsigned short &h, unsigned short &l){
    unsigned u = __float_as_uint(v);
    unsigned hr = (u + 0x7fffu + ((u>>16)&1u)) >> 16;
    h = (unsigned short)hr;
    float hf = __uint_as_float(hr << 16);
    unsigned u2 = __float_as_uint(v - hf);
    l = (unsigned short)((u2 + 0x7fffu + ((u2>>16)&1u)) >> 16);
}

// ---------- LDS-tiled transpose x5 (B,C,L) -> x5t (B,L,C) fp32 + B-form bf16 ----------
__global__ void k_transpose_in(const float* __restrict__ x5, float* __restrict__ x5t,
                               unsigned short* __restrict__ x5tB){
    __shared__ float t[32][33];
    const int b = blockIdx.z;
    const int c0 = blockIdx.x*32, l0 = blockIdx.y*32;
    const int tx = threadIdx.x & 31, ty = threadIdx.x >> 5;   // 32x8
    #pragma unroll
    for (int i=ty; i<32; i+=8)
        t[i][tx] = x5[((size_t)b*NC + c0 + i)*NL + l0 + tx];
    __syncthreads();
    #pragma unroll
    for (int i=ty; i<32; i+=8){
        float v = t[tx][i];
        x5t[((size_t)b*NL + l0 + i)*NC + c0 + tx] = v;
        unsigned short hh, ll; split_bf(v, hh, ll);
        size_t rb = ((size_t)b*NL + l0 + i)*1536 + c0 + tx;
        x5tB[rb] = hh; x5tB[rb+512] = ll; x5tB[rb+1024] = hh;
    }
}

// ---------- fp32 -> split-bf16 forms ----------
// A-form row layout (3K): [hi | hi | lo];  B-form: [hi | lo | hi]
template<int FORM>
__global__ void k_split(const float* __restrict__ in, unsigned short* __restrict__ oA,
                        unsigned short* __restrict__ oB, int K, int total4){
    int t = blockIdx.x*256 + threadIdx.x;
    if (t >= total4) return;
    int kq = K >> 2;
    int r = t / kq; int k4 = (t - r*kq) << 2;
    float4 v = *(const float4*)(in + (size_t)r*K + k4);
    float vv[4] = {v.x, v.y, v.z, v.w};
    unsigned short h[4], lo[4];
    #pragma unroll
    for (int i=0;i<4;i++) split_bf(vv[i], h[i], lo[i]);
    unsigned hp0 = h[0] | ((unsigned)h[1]<<16), hp1 = h[2] | ((unsigned)h[3]<<16);
    unsigned lp0 = lo[0] | ((unsigned)lo[1]<<16), lp1 = lo[2] | ((unsigned)lo[3]<<16);
    size_t base = (size_t)r*3*K + k4;
    if (FORM == 0 || FORM == 2){
        unsigned* p0 = (unsigned*)(oA + base);
        unsigned* p1 = (unsigned*)(oA + base + K);
        unsigned* p2 = (unsigned*)(oA + base + 2*K);
        p0[0]=hp0; p0[1]=hp1;  p1[0]=hp0; p1[1]=hp1;  p2[0]=lp0; p2[1]=lp1;
    }
    if (FORM == 1 || FORM == 2){
        unsigned short* o = (FORM==2) ? oB : oA;
        unsigned* p0 = (unsigned*)(o + base);
        unsigned* p1 = (unsigned*)(o + base + K);
        unsigned* p2 = (unsigned*)(o + base + 2*K);
        p0[0]=hp0; p0[1]=hp1;  p1[0]=lp0; p1[1]=lp1;  p2[0]=hp0; p2[1]=hp1;
    }
}

// ---------- MFMA bf16x3 NT GEMM, register-prefetch pipelined ----------
// MODE 0: conv1x1 (+bias+residual) | 1: in_proj split | 3: out_proj (+residual)
// MODE 4: gram, compact upper-tri 1D grid, row/col max -> mbuf
template<int MODE>
__launch_bounds__(256)
__global__ void mfma_nt(const unsigned short* __restrict__ A, const unsigned short* __restrict__ Bm,
                        const float* __restrict__ R0, const float* __restrict__ R1,
                        float* __restrict__ out0, float* __restrict__ out1,
                        unsigned* __restrict__ mbuf, int K3)
{
    int bi, bj;
    if (MODE == 4){
        int rem = blockIdx.x, len = 36; bi = 0;
        while (rem >= len){ rem -= len; len--; bi++; }
        bj = bi + rem;
    } else { bi = blockIdx.x; bj = blockIdx.y; }
    const int m0 = bi*128, n0 = bj*128;
    __shared__ __align__(16) unsigned short As[128*32];
    __shared__ __align__(16) unsigned short Bs[128*32];
    const int tid = threadIdx.x;
    const int w = tid >> 6, l = tid & 63;
    const int mw = (w>>1)*64, nw = (w&1)*64;
    const int fr = l & 15, fq = l >> 4;

    f32x4 acc[4][4];
    #pragma unroll
    for (int i=0;i<4;i++)
        #pragma unroll
        for (int j=0;j<4;j++)
            #pragma unroll
            for (int c=0;c<4;c++) acc[i][j][c] = 0.f;

    const int c0 = tid, c1 = tid + 256;
    const int r0 = c0 >> 2, o0 = (c0 & 3) * 8;
    const int r1 = c1 >> 2, o1 = (c1 & 3) * 8;
    const unsigned short* pA0 = A  + (size_t)(m0 + r0)*K3 + o0;
    const unsigned short* pA1 = A  + (size_t)(m0 + r1)*K3 + o1;
    const unsigned short* pB0 = Bm + (size_t)(n0 + r0)*K3 + o0;
    const unsigned short* pB1 = Bm + (size_t)(n0 + r1)*K3 + o1;

    float4 a0 = *(const float4*)(pA0);
    float4 a1 = *(const float4*)(pA1);
    float4 b0 = *(const float4*)(pB0);
    float4 b1 = *(const float4*)(pB1);

    for (int k0 = 0; k0 < K3; k0 += 32){
        __syncthreads();
        *(float4*)&As[c0*8] = a0;
        *(float4*)&As[c1*8] = a1;
        *(float4*)&Bs[c0*8] = b0;
        *(float4*)&Bs[c1*8] = b1;
        __syncthreads();
        if (k0 + 32 < K3){
            a0 = *(const float4*)(pA0 + k0 + 32);
            a1 = *(const float4*)(pA1 + k0 + 32);
            b0 = *(const float4*)(pB0 + k0 + 32);
            b1 = *(const float4*)(pB1 + k0 + 32);
        }
        bf16x8 af[4], bf[4];
        #pragma unroll
        for (int i=0;i<4;i++){
            af[i] = *(const bf16x8*)&As[(mw + i*16 + fr)*32 + fq*8];
            bf[i] = *(const bf16x8*)&Bs[(nw + i*16 + fr)*32 + fq*8];
        }
        #pragma unroll
        for (int i=0;i<4;i++)
            #pragma unroll
            for (int j=0;j<4;j++)
                acc[i][j] = __builtin_amdgcn_mfma_f32_16x16x32_bf16(af[i], bf[j], acc[i][j], 0, 0, 0);
    }

    if (MODE == 4){
        const int b2c = (n0 + nw) / NL;
        #pragma unroll
        for (int mi=0; mi<4; mi++){
            #pragma unroll
            for (int i=0;i<4;i++){
                float v = fmaxf(fmaxf(acc[mi][0][i], acc[mi][1][i]),
                                fmaxf(acc[mi][2][i], acc[mi][3][i]));
                v = fmaxf(v, __shfl_xor(v, 1));
                v = fmaxf(v, __shfl_xor(v, 2));
                v = fmaxf(v, __shfl_xor(v, 4));
                v = fmaxf(v, __shfl_xor(v, 8));
                if (fr == 0)
                    atomicMax(&mbuf[(size_t)(m0 + mw + mi*16 + fq*4 + i)*NB + b2c], enc_f(v));
            }
        }
        const int b2r = (m0 + mw) / NL;
        #pragma unroll
        for (int ni=0; ni<4; ni++){
            float cm = -3.4e38f;
            #pragma unroll
            for (int mi=0; mi<4; mi++)
                #pragma unroll
                for (int i=0;i<4;i++) cm = fmaxf(cm, acc[mi][ni][i]);
            cm = fmaxf(cm, __shfl_xor(cm, 16));
            cm = fmaxf(cm, __shfl_xor(cm, 32));
            if (fq == 0)
                atomicMax(&mbuf[(size_t)(n0 + nw + ni*16 + fr)*NB + b2r], enc_f(cm));
        }
        return;
    }

    #pragma unroll
    for (int mi=0; mi<4; mi++){
        const int m = m0 + mw + mi*16 + fq*4;
        #pragma unroll
        for (int ni=0; ni<4; ni++){
            const int n = n0 + nw + ni*16 + fr;
            f32x4 a = acc[mi][ni];
            if (MODE == 0){
                float4 cb = *(const float4*)(R0 + m);
                float4 rs = *(const float4*)(R1 + (size_t)n*NC + m);
                float4 ov = make_float4(a[0]+cb.x+rs.x, a[1]+cb.y+rs.y, a[2]+cb.z+rs.z, a[3]+cb.w+rs.w);
                *(float4*)(out0 + (size_t)n*NC + m) = ov;
            } else if (MODE == 1){
                float4 ov = make_float4(a[0], a[1], a[2], a[3]);
                if (m < ND) *(float4*)(out0 + (size_t)n*ND + m) = ov;
                else        *(float4*)(out1 + (size_t)n*ND + (m - ND)) = ov;
            } else { // MODE 3
                float4 rs = *(const float4*)(R1 + (size_t)n*NC + m);
                float4 ov = make_float4(a[0]+rs.x, a[1]+rs.y, a[2]+rs.z, a[3]+rs.w);
                *(float4*)(out0 + (size_t)n*NC + m) = ov;
            }
        }
    }
}

// ---------- fp32 NT tiled GEMM (x_proj only, MODE 2) ----------
template<int MODE>
__launch_bounds__(256)
__global__ void gemm_nt(const float* __restrict__ A0, const float* __restrict__ B0,
                        const float* __restrict__ R,
                        float* __restrict__ out0, float* __restrict__ out1,
                        unsigned* __restrict__ mbuf, int K)
{
    __shared__ __align__(16) float As[16][68];
    __shared__ __align__(16) float Bs[16][68];
    const int tid = threadIdx.x;
    const int m0 = blockIdx.x * 64;
    const int n0 = blockIdx.y * 64;
    const float* A = A0;
    const float* B = B0;
    int kdir = 0;
    if (MODE == 2) {
        const int bk = blockIdx.z;         // b*4 + k
        kdir = bk & 3; const int bb = bk >> 2;
        A = A0 + (size_t)kdir * 64 * 1024;
        B = B0 + (size_t)bb * NL * 1024;
    }
    const int lrow = tid >> 2;
    const int lk4  = (tid & 3) << 2;
    int brow = n0 + lrow;
    if (MODE == 2) brow = scan_idx(brow, kdir);
    const float* aptr = A + (size_t)(m0 + lrow) * K + lk4;
    const float* bptr = B + (size_t)brow * K + lk4;

    float acc[4][4];
    #pragma unroll
    for (int i=0;i<4;i++){
        #pragma unroll
        for (int j=0;j<4;j++) acc[i][j]=0.f;
    }
    const int tx = tid & 15, ty = tid >> 4;

    for (int k0 = 0; k0 < K; k0 += 16) {
        float4 av = *(const float4*)(aptr + k0);
        float4 bv = *(const float4*)(bptr + k0);
        __syncthreads();
        As[lk4+0][lrow]=av.x; As[lk4+1][lrow]=av.y; As[lk4+2][lrow]=av.z; As[lk4+3][lrow]=av.w;
        Bs[lk4+0][lrow]=bv.x; Bs[lk4+1][lrow]=bv.y; Bs[lk4+2][lrow]=bv.z; Bs[lk4+3][lrow]=bv.w;
        __syncthreads();
        #pragma unroll
        for (int kk=0;kk<16;kk++){
            float4 a = *(const float4*)&As[kk][ty<<2];
            float4 b = *(const float4*)&Bs[kk][tx<<2];
            acc[0][0] = fmaf(a.x,b.x,acc[0][0]); acc[0][1] = fmaf(a.x,b.y,acc[0][1]);
            acc[0][2] = fmaf(a.x,b.z,acc[0][2]); acc[0][3] = fmaf(a.x,b.w,acc[0][3]);
            acc[1][0] = fmaf(a.y,b.x,acc[1][0]); acc[1][1] = fmaf(a.y,b.y,acc[1][1]);
            acc[1][2] = fmaf(a.y,b.z,acc[1][2]); acc[1][3] = fmaf(a.y,b.w,acc[1][3]);
            acc[2][0] = fmaf(a.z,b.x,acc[2][0]); acc[2][1] = fmaf(a.z,b.y,acc[2][1]);
            acc[2][2] = fmaf(a.z,b.z,acc[2][2]); acc[2][3] = fmaf(a.z,b.w,acc[2][3]);
            acc[3][0] = fmaf(a.w,b.x,acc[3][0]); acc[3][1] = fmaf(a.w,b.y,acc[3][1]);
            acc[3][2] = fmaf(a.w,b.z,acc[3][2]); acc[3][3] = fmaf(a.w,b.w,acc[3][3]);
        }
    }

    #pragma unroll
    for (int j=0;j<4;j++){
        const int n  = n0 + (tx<<2) + j;
        const int mm = m0 + (ty<<2);
        float4 v = make_float4(acc[0][j], acc[1][j], acc[2][j], acc[3][j]);
        if (MODE == 2){
            *(float4*)(out0 + ((size_t)blockIdx.z*NL + n)*64 + mm) = v;
        }
    }
}

// ---------- layernorm over C=512, directly to B-form bf16x3 ----------
__global__ void k_ln512b(const float* __restrict__ x, const float* __restrict__ g,
                         const float* __restrict__ bb, unsigned short* __restrict__ outB){
    int n = blockIdx.x; int tid = threadIdx.x;     // 256 threads
    const float* row = x + (size_t)n*NC;
    float v0 = row[tid], v1 = row[tid+256];
    __shared__ float s1[256], s2[256];
    s1[tid] = v0+v1; s2[tid] = v0*v0 + v1*v1;
    __syncthreads();
    for (int s=128;s>0;s>>=1){ if (tid<s){ s1[tid]+=s1[tid+s]; s2[tid]+=s2[tid+s]; } __syncthreads(); }
    float mean = s1[0]*(1.f/NC);
    float var  = fmaxf(s2[0]*(1.f/NC) - mean*mean, 0.f);
    float rs   = rsqrtf(var + 1e-5f);
    float r0 = (v0-mean)*rs*g[tid]     + bb[tid];
    float r1 = (v1-mean)*rs*g[tid+256] + bb[tid+256];
    unsigned short h0,l0,h1,l1; split_bf(r0,h0,l0); split_bf(r1,h1,l1);
    size_t base = (size_t)n*1536;
    outB[base+tid]     =h0; outB[base+512+tid]     =l0; outB[base+1024+tid]     =h0;
    outB[base+tid+256] =h1; outB[base+512+tid+256] =l1; outB[base+1024+tid+256] =h1;
}

// ---------- depthwise 3x3 SAME + bias + SiLU, rolling window ----------
__global__ void k_dwconv(const float* __restrict__ xi, const float* __restrict__ w,
                         const float* __restrict__ bias, float* __restrict__ xcl){
    int d = blockIdx.x*256 + threadIdx.x;          // 0..1023
    int h = blockIdx.y; int b = blockIdx.z;
    float W[9];
    #pragma unroll
    for (int i=0;i<9;i++) W[i] = w[d*9+i];
    float bs = bias[d];
    const size_t rb = ((size_t)b*NL)*ND + d;
    const bool hm = h > 0, hp = h < NH-1;
    float p0=0.f,p1=0.f,p2=0.f;
    float c0 = hm ? xi[rb + (size_t)((h-1)*NW)*ND] : 0.f;
    float c1 = xi[rb + (size_t)(h*NW)*ND];
    float c2 = hp ? xi[rb + (size_t)((h+1)*NW)*ND] : 0.f;
    for (int wc=0; wc<NW; wc++){
        float n0,n1,n2;
        if (wc < NW-1){
            n0 = hm ? xi[rb + (size_t)((h-1)*NW+wc+1)*ND] : 0.f;
            n1 = xi[rb + (size_t)(h*NW+wc+1)*ND];
            n2 = hp ? xi[rb + (size_t)((h+1)*NW+wc+1)*ND] : 0.f;
        } else { n0=0.f;n1=0.f;n2=0.f; }
        float acc = bs;
        acc = fmaf(W[0],p0, fmaf(W[1],c0, fmaf(W[2],n0, acc)));
        acc = fmaf(W[3],p1, fmaf(W[4],c1, fmaf(W[5],n1, acc)));
        acc = fmaf(W[6],p2, fmaf(W[7],c2, fmaf(W[8],n2, acc)));
        xcl[rb + (size_t)(h*NW+wc)*ND] = silu_f(acc);
        p0=c0;p1=c1;p2=c2; c0=n0;c1=n1;c2=n2;
    }
}

// packed dA power tree from e1 -> f32x2 dA2[8], pairs (2n,2n+1)
#define DA_POWERS2 \
    float e2=e1*e1; float e3=e2*e1; float e4=e2*e2; \
    float e6=e4*e2; float e7=e4*e3; float e8=e4*e4; float e12=e8*e4; \
    f32x2 dA2[8]; \
    dA2[0]=(f32x2){e1,e2};       dA2[1]=(f32x2){e3,e4}; \
    dA2[2]=(f32x2){e4*e1,e6};    dA2[3]=(f32x2){e7,e8}; \
    dA2[4]=(f32x2){e8*e1,e8*e2}; dA2[5]=(f32x2){e8*e3,e12}; \
    dA2[6]=(f32x2){e12*e1,e12*e2}; dA2[7]=(f32x2){e12*e3,e8*e8};

// packed dot: rq2[0..15] (dt row as f32x2) with wdt2[16]
#define DOT4P(rq2, dtb, out) { \
    f32x2 sA={0.f,0.f},sB={0.f,0.f},sC={0.f,0.f},sD={0.f,0.f}; \
    sA += rq2[0]*wdt2[0];  sB += rq2[1]*wdt2[1];  sC += rq2[2]*wdt2[2];  sD += rq2[3]*wdt2[3]; \
    sA += rq2[4]*wdt2[4];  sB += rq2[5]*wdt2[5];  sC += rq2[6]*wdt2[6];  sD += rq2[7]*wdt2[7]; \
    sA += rq2[8]*wdt2[8];  sB += rq2[9]*wdt2[9];  sC += rq2[10]*wdt2[10]; sD += rq2[11]*wdt2[11]; \
    sA += rq2[12]*wdt2[12]; sB += rq2[13]*wdt2[13]; sC += rq2[14]*wdt2[14]; sD += rq2[15]*wdt2[15]; \
    out = ((sA.x+sA.y)+(sB.x+sB.y)) + ((sC.x+sC.y)+(sD.x+sD.y)) + dtb; }

// ---------- chunked selective scan, pass 1 (128 threads, packed fp32) ----------
__launch_bounds__(128)
__global__ void k_scan_p1(const float* __restrict__ xcl, const float* __restrict__ xdbl,
                          const float* __restrict__ dtw, const float* __restrict__ dtb,
                          const float* __restrict__ alogs,
                          float* __restrict__ hfin, float* __restrict__ prodA){
    const int d = blockIdx.x*128 + threadIdx.x;
    const int chunk = blockIdx.y;
    const int bk = blockIdx.z;
    const int k = bk & 3, b = bk >> 2;
    const int kd = k*ND + d;
    f32x2 wdt2[16];
    {
        const float4* p = (const float4*)(dtw + (size_t)kd*32);
        #pragma unroll
        for (int i=0;i<8;i++){
            float4 v=p[i];
            wdt2[2*i]   = (f32x2){v.x, v.y};
            wdt2[2*i+1] = (f32x2){v.z, v.w};
        }
    }
    float An[16]; bool ladder = true;
    {
        const float4* p = (const float4*)(alogs + (size_t)kd*16);
        #pragma unroll
        for (int i=0;i<4;i++){
            float4 v=p[i];
            An[4*i]=-__expf(v.x); An[4*i+1]=-__expf(v.y); An[4*i+2]=-__expf(v.z); An[4*i+3]=-__expf(v.w);
        }
        #pragma unroll
        for (int n=0;n<16;n++) ladder = ladder && (fabsf(An[n] + (float)(n+1)) < 1e-3f*(n+1));
    }
    const float dtbias = dtb[kd];
    __shared__ __align__(16) float rows[CL*64];
    {
        const float4* src = (const float4*)(xdbl + ((size_t)bk*NL + chunk*CL)*64);
        for (int i = threadIdx.x; i < CL*16; i += 128) ((float4*)rows)[i] = src[i];
    }
    __syncthreads();
    if (ladder){
        f32x2 h2[8], pA2[8];
        #pragma unroll
        for (int n=0;n<8;n++){ h2[n]=(f32x2){0.f,0.f}; pA2[n]=(f32x2){1.f,1.f}; }
        float u = xcl[((size_t)b*NL + scan_idx(chunk*CL, k))*ND + d];
        for (int t=0;t<CL;t++){
            const f32x2* rq2 = (const f32x2*)(rows + t*64);
            float dr; DOT4P(rq2, dtbias, dr);
            float u_cur = u;
            if (t+1 < CL) u = xcl[((size_t)b*NL + scan_idx(chunk*CL+t+1, k))*ND + d];
            float sp = softplus_f(dr);
            float du = sp * u_cur;
            float e1 = __expf(-sp);
            DA_POWERS2
            f32x2 du2 = (f32x2){du, du};
            #pragma unroll
            for (int n=0;n<8;n++){
                pA2[n] *= dA2[n];
                h2[n] = dA2[n]*h2[n] + du2*rq2[16+n];
            }
        }
        size_t base = (size_t)(bk*NCH + chunk)*16*1024 + d;
        #pragma unroll
        for (int n=0;n<8;n++){
            hfin[base + (2*n)*1024]   = h2[n].x;  hfin[base + (2*n+1)*1024] = h2[n].y;
            prodA[base + (2*n)*1024]  = pA2[n].x; prodA[base + (2*n+1)*1024]= pA2[n].y;
        }
    } else {
        float h[16], pA[16];
        #pragma unroll
        for (int n=0;n<16;n++){ h[n]=0.f; pA[n]=1.f; }
        for (int t=0;t<CL;t++){
            const f32x2* rq2 = (const f32x2*)(rows + t*64);
            float dr; DOT4P(rq2, dtbias, dr);
            float sp = softplus_f(dr);
            int idx = scan_idx(chunk*CL + t, k);
            float u  = xcl[((size_t)b*NL + idx)*ND + d];
            float du = sp * u;
            const float* row = rows + t*64;
            #pragma unroll
            for (int n=0;n<16;n++){
                float dA = __expf(sp * An[n]);
                pA[n] *= dA;
                h[n] = fmaf(dA, h[n], du*row[32+n]);
            }
        }
        size_t base = (size_t)(bk*NCH + chunk)*16*1024 + d;
        #pragma unroll
        for (int n=0;n<16;n++){ hfin[base + n*1024] = h[n]; prodA[base + n*1024] = pA[n]; }
    }
}

// ---------- chunked scan, mid ----------
__global__ void k_scan_mid(float* __restrict__ hfin, const float* __restrict__ prodA){
    int id = blockIdx.x*256 + threadIdx.x;
    int d = id & 1023, nn = (id >> 10) & 15, bk = id >> 14;
    float h = 0.f;
    for (int j=0;j<NCH;j++){
        size_t idx = (size_t)((bk*NCH + j)*16 + nn)*1024 + d;
        float hf = hfin[idx], pa = prodA[idx];
        hfin[idx] = h;
        h = fmaf(pa, h, hf);
    }
}

// ---------- chunked scan, pass 2 (128 threads, packed fp32) ----------
__launch_bounds__(128)
__global__ void k_scan_p2(const float* __restrict__ xcl, const float* __restrict__ xdbl,
                          const float* __restrict__ dtw, const float* __restrict__ dtb,
                          const float* __restrict__ alogs,
                          const float* __restrict__ hfin, float* __restrict__ yacc){
    const int d = blockIdx.x*128 + threadIdx.x;
    const int chunk = blockIdx.y;
    const int bk = blockIdx.z;
    const int k = bk & 3, b = bk >> 2;
    const int kd = k*ND + d;
    f32x2 wdt2[16];
    {
        const float4* p = (const float4*)(dtw + (size_t)kd*32);
        #pragma unroll
        for (int i=0;i<8;i++){
            float4 v=p[i];
            wdt2[2*i]   = (f32x2){v.x, v.y};
            wdt2[2*i+1] = (f32x2){v.z, v.w};
        }
    }
    float An[16]; bool ladder = true;
    {
        const float4* p = (const float4*)(alogs + (size_t)kd*16);
        #pragma unroll
        for (int i=0;i<4;i++){
            float4 v=p[i];
            An[4*i]=-__expf(v.x); An[4*i+1]=-__expf(v.y); An[4*i+2]=-__expf(v.z); An[4*i+3]=-__expf(v.w);
        }
        #pragma unroll
        for (int n=0;n<16;n++) ladder = ladder && (fabsf(An[n] + (float)(n+1)) < 1e-3f*(n+1));
    }
    const float dtbias = dtb[kd];
    __shared__ __align__(16) float rows[CL*64];
    {
        const float4* src = (const float4*)(xdbl + ((size_t)bk*NL + chunk*CL)*64);
        for (int i = threadIdx.x; i < CL*16; i += 128) ((float4*)rows)[i] = src[i];
    }
    __syncthreads();
    if (ladder){
        f32x2 h2[8];
        {
            size_t base = (size_t)(bk*NCH + chunk)*16*1024 + d;
            #pragma unroll
            for (int n=0;n<8;n++)
                h2[n] = (f32x2){hfin[base + (2*n)*1024], hfin[base + (2*n+1)*1024]};
        }
        int idx = scan_idx(chunk*CL, k);
        float u = xcl[((size_t)b*NL + idx)*ND + d];
        for (int t=0;t<CL;t++){
            const f32x2* rq2 = (const f32x2*)(rows + t*64);
            float dr; DOT4P(rq2, dtbias, dr);
            float u_cur = u; int idx_cur = idx;
            if (t+1 < CL){
                idx = scan_idx(chunk*CL+t+1, k);
                u = xcl[((size_t)b*NL + idx)*ND + d];
            }
            float sp = softplus_f(dr);
            float du = sp * u_cur;
            float e1 = __expf(-sp);
            DA_POWERS2
            f32x2 du2 = (f32x2){du, du};
            f32x2 y2 = (f32x2){0.f, 0.f};
            #pragma unroll
            for (int n=0;n<8;n++){
                h2[n] = dA2[n]*h2[n] + du2*rq2[16+n];
                y2 += h2[n]*rq2[24+n];
            }
            atomicAdd(&yacc[((size_t)b*NL + idx_cur)*ND + d], y2.x + y2.y);
        }
    } else {
        float h[16];
        {
            size_t base = (size_t)(bk*NCH + chunk)*16*1024 + d;
            #pragma unroll
            for (int n=0;n<16;n++) h[n] = hfin[base + n*1024];
        }
        for (int t=0;t<CL;t++){
            const f32x2* rq2 = (const f32x2*)(rows + t*64);
            float dr; DOT4P(rq2, dtbias, dr);
            float sp = softplus_f(dr);
            int idx = scan_idx(chunk*CL + t, k);
            size_t base = ((size_t)b*NL + idx)*ND + d;
            float u  = xcl[base];
            float du = sp * u;
            const float* row = rows + t*64;
            float y = 0.f;
            #pragma unroll
            for (int n=0;n<16;n++){
                float dA = __expf(sp * An[n]);
                h[n] = fmaf(dA, h[n], du*row[32+n]);
                y = fmaf(h[n], row[48+n], y);
            }
            atomicAdd(&yacc[base], y);
        }
    }
}

// ---------- combine y + Ds*u, LN over D, gate with silu(z) -> zB (B-form bf16x3) ----------
__global__ void k_combine(const float* __restrict__ y, const float* __restrict__ xcl,
                          const float* __restrict__ Ds,
                          const float* __restrict__ g, const float* __restrict__ bb,
                          const float* __restrict__ z, unsigned short* __restrict__ zB){
    int n = blockIdx.x;
    size_t base = (size_t)n*ND;
    int tid = threadIdx.x;
    float v[4]; float sum=0.f, sq=0.f;
    #pragma unroll
    for (int j=0;j<4;j++){
        int d = tid + 256*j;
        float ds = Ds[d] + Ds[ND+d] + Ds[2*ND+d] + Ds[3*ND+d];
        float val = y[base+d] + ds*xcl[base+d];
        v[j]=val; sum+=val; sq+=val*val;
    }
    __shared__ float s1[256], s2[256];
    s1[tid]=sum; s2[tid]=sq; __syncthreads();
    for (int st=128;st>0;st>>=1){ if(tid<st){ s1[tid]+=s1[tid+st]; s2[tid]+=s2[tid+st]; } __syncthreads(); }
    float mean = s1[0]*(1.f/ND);
    float var  = fmaxf(s2[0]*(1.f/ND) - mean*mean, 0.f);
    float rs   = rsqrtf(var + 1e-5f);
    size_t zb = (size_t)n*3072;
    #pragma unroll
    for (int j=0;j<4;j++){
        int d = tid + 256*j;
        float ln = (v[j]-mean)*rs*g[d] + bb[d];
        float res = ln * silu_f(z[base+d]);
        unsigned short hh,ll; split_bf(res,hh,ll);
        zB[zb + d] = hh; zB[zb + 1024 + d] = ll; zB[zb + 2048 + d] = hh;
    }
}

// ---------- fused xwpre + argmax mask + tie list (one wave per b) ----------
__global__ void k_mask2(const unsigned* __restrict__ M, float* __restrict__ maskf,
                        int* __restrict__ hitcnt, int* __restrict__ hitidx){
    int b = blockIdx.x; int tid = threadIdx.x;     // 64 threads
    __shared__ int lcnt;
    if (tid == 0) lcnt = 0;
    __syncthreads();
    float loc[9];
    float m = -3.4e38f;
    #pragma unroll
    for (int j=0;j<9;j++){
        int l = tid + j*64;
        float s = 0.f;
        #pragma unroll
        for (int b2=0;b2<NB;b2++) s += dec_f(M[(size_t)(b*NL+l)*NB + b2]);
        loc[j] = s; m = fmaxf(m, s);
    }
    #pragma unroll
    for (int s=32;s>0;s>>=1) m = fmaxf(m, __shfl_xor(m, s));
    #pragma unroll
    for (int j=0;j<9;j++){
        int l = tid + j*64;
        bool hit = (loc[j] == m);
        maskf[b*NL + l] = hit ? 1.f : 0.f;
        if (hit){
            int pos = atomicAdd(&lcnt, 1);
            hitidx[b*NL + pos] = l;
        }
    }
    __syncthreads();
    if (tid == 0) hitcnt[b] = lcnt;
}

// ---------- channel-norm: norm0 (B,L,C) ----------
__global__ void k_norm0(const float* __restrict__ x5r, float* __restrict__ norm0){
    int n = blockIdx.x; int tid = threadIdx.x;     // 256
    float v0 = x5r[(size_t)n*NC+tid], v1 = x5r[(size_t)n*NC+tid+256];
    __shared__ float s1[256];
    s1[tid] = v0*v0 + v1*v1; __syncthreads();
    for (int st=128;st>0;st>>=1){ if(tid<st) s1[tid]+=s1[tid+st]; __syncthreads(); }
    float inv = 1.f / fmaxf(sqrtf(s1[0]), 1e-12f);
    norm0[(size_t)n*NC+tid]     = v0*inv;
    norm0[(size_t)n*NC+tid+256] = v1*inv;
}

// ---------- seeds[b,c] = sum over tie-list rows of norm0 ----------
__global__ void k_seeds(const float* __restrict__ norm0, const int* __restrict__ hitcnt,
                        const int* __restrict__ hitidx, float* __restrict__ seeds){
    int b = blockIdx.x; int c = threadIdx.x;       // 512
    int cnt = hitcnt[b];
    float acc = 0.f;
    for (int i=0;i<cnt;i++){
        int l = hitidx[b*NL + i];
        acc += norm0[((size_t)b*NL+l)*NC + c];
    }
    seeds[b*NC + c] = acc;
}

// ---------- cor[b,l] = mean_o relu(norm0 . seeds_o), wave-per-o ----------
__global__ void k_cor(const float* __restrict__ norm0, const float* __restrict__ seeds,
                      float* __restrict__ cor){
    int n = blockIdx.x; int tid = threadIdx.x;     // 512 = 8 waves
    int o = tid >> 6, lane = tid & 63;
    float acc = 0.f;
    #pragma unroll
    for (int i=0;i<8;i++){
        int c = lane + 64*i;
        acc += norm0[(size_t)n*NC + c] * seeds[o*NC + c];
    }
    #pragma unroll
    for (int s=32;s>0;s>>=1) acc += __shfl_xor(acc, s);
    __shared__ float sr[8];
    if (lane == 0) sr[o] = fmaxf(acc, 0.f);
    __syncthreads();
    if (tid == 0){
        float r = 0.f;
        #pragma unroll
        for (int o2=0;o2<8;o2++) r += sr[o2];
        cor[n] = r * (1.f/8.f);
    }
}

// ---------- cormap per b ----------
__global__ void k_cormap(const float* __restrict__ cor, float* __restrict__ cmap){
    int b = blockIdx.x, tid = threadIdx.x;         // 64
    float mn = 1e30f, mx = -1e30f;
    for (int i=tid;i<NL;i+=64){ float v=cor[b*NL+i]; mn=fminf(mn,v); mx=fmaxf(mx,v); }
    __shared__ float sn[64], sx[64];
    sn[tid]=mn; sx[tid]=mx; __syncthreads();
    for (int st=32;st>0;st>>=1){ if(tid<st){ sn[tid]=fminf(sn[tid],sn[tid+st]); sx[tid]=fmaxf(sx[tid],sx[tid+st]); } __syncthreads(); }
    float MN=sn[0], MX=sx[0];
    float inv = 1.f/(MX-MN+1e-12f);
    for (int i=tid;i<NL;i+=64) cmap[b*NL+i] = (cor[b*NL+i]-MN)*inv;
}

// ---------- proto accumulation ----------
__global__ void k_proto(const float* __restrict__ x5r, const float* __restrict__ cmap,
                        float* __restrict__ pacc){
    int c = threadIdx.x;                            // 512
    int chunk = blockIdx.x;                         // 72 chunks of 64
    float acc = 0.f;
    for (int i=0;i<64;i++){
        int n = chunk*64 + i;
        acc += x5r[(size_t)n*NC + c] * cmap[n];
    }
    atomicAdd(&pacc[c], acc);
}

// ---------- final outputs ----------
__global__ void k_final(const float* __restrict__ x5r, const float* __restrict__ cmap,
                        const float* __restrict__ pacc, const float* __restrict__ maskf,
                        float* __restrict__ out){
    int id = blockIdx.x*256 + threadIdx.x;          // over (b,c,l) = 2359296
    int l = id % NL; int bc = id / NL; int c = bc & 511; int b = bc >> 9;
    float v  = x5r[((size_t)b*NL + l)*NC + c];
    float p  = pacc[c] * (1.f/(float)NBL);
    float cm = cmap[b*NL + l];
    out[id] = v;                                    // output 0: x5
    out[2359296 + 512 + id] = v*(p + cm);           // output 2: x5*proto1 + x51
    if (id < 512)  out[2359296 + id] = pacc[id] * (1.f/(float)NBL);       // output 1
    if (id < NBL)  out[2359296 + 512 + 2359296 + id] = maskf[id];         // output 3
}

// ---------------- launcher ----------------
extern "C" void kernel_launch(void* const* d_in, const int* in_sizes, int n_in,
                              void* d_out, int out_size, void* d_ws, size_t ws_size,
                              hipStream_t stream) {
    const float* x5        = (const float*)d_in[0];
    const float* conv_w    = (const float*)d_in[1];
    const float* conv_b    = (const float*)d_in[2];
    const float* ln1_g     = (const float*)d_in[3];
    const float* ln1_b     = (const float*)d_in[4];
    const float* in_proj_w = (const float*)d_in[5];
    const float* dwconv_w  = (const float*)d_in[6];
    const float* dwconv_b  = (const float*)d_in[7];
    const float* x_proj_w  = (const float*)d_in[8];
    const float* dt_proj_w = (const float*)d_in[9];
    const float* dt_proj_b = (const float*)d_in[10];
    const float* A_logs    = (const float*)d_in[11];
    const float* Ds        = (const float*)d_in[12];
    const float* out_norm_g= (const float*)d_in[13];
    const float* out_norm_b= (const float*)d_in[14];
    const float* out_proj_w= (const float*)d_in[15];

    float* ws = (float*)d_ws;
    const size_t O_X5R  = 0;          // x5r (permanent)
    const size_t O_XLN  = 2359296;    // xqf
    const size_t O_XI   = 4718592;    // xi -> yacc -> wAo
    const size_t O_Z    = 9437184;    // z
    const size_t O_XCL  = 14155776;   // wAi -> xcl -> nrm0
    const size_t O_XDBL = 18874368;   // xdbl
    const size_t O_HF   = 20054016;   // x5t -> xlnB -> hfin -> zB(span) -> xqfA
    const size_t O_PA   = 24248320;   // x5tB+wAc -> prodA -> zB(tail) -> xqfB
    const size_t O_MBUF = 28442624;
    const size_t O_MASK = 28484096;
    const size_t O_COR  = 28488704;
    const size_t O_CMAP = 28493312;
    const size_t O_SEED = 28497920;
    const size_t O_PACC = 28502016;
    const size_t O_HITC = 28502528;   // 8 ints
    const size_t O_HITI = 28502544;   // 4608 ints

    float* x5r  = ws + O_X5R;
    float* xqf  = ws + O_XLN;
    float* xi   = ws + O_XI;
    float* yacc = ws + O_XI;
    unsigned short* wAo = (unsigned short*)(ws + O_XI);
    float* z    = ws + O_Z;
    float* xcl  = ws + O_XCL;
    unsigned short* wAi = (unsigned short*)(ws + O_XCL);
    float* nrm0 = ws + O_XCL;
    float* xdbl = ws + O_XDBL;
    float* x5t  = ws + O_HF;
    float* hfin = ws + O_HF;
    unsigned short* xlnB = (unsigned short*)(ws + O_HF);
    unsigned short* zB   = (unsigned short*)(ws + O_HF);
    unsigned short* xqfA = (unsigned short*)(ws + O_HF);
    float* prodA = ws + O_PA;
    unsigned short* x5tB = (unsigned short*)(ws + O_PA);
    unsigned short* wAc  = (unsigned short*)(ws + O_PA) + 7077888;
    unsigned short* xqfB = (unsigned short*)(ws + O_PA);
    unsigned* mbuf = (unsigned*)(ws + O_MBUF);
    float* maskf= ws + O_MASK;
    float* cor  = ws + O_COR;
    float* cmap = ws + O_CMAP;
    float* seeds= ws + O_SEED;
    float* pacc = ws + O_PACC;
    int* hitcnt = (int*)(ws + O_HITC);
    int* hitidx = (int*)(ws + O_HITI);

    (void)hipMemsetAsync(mbuf, 0, 36864*sizeof(unsigned), stream);
    (void)hipMemsetAsync(pacc, 0, 512*sizeof(float), stream);

    // 1. transpose x5 -> x5t (fp32) + x5tB (B-form bf16x3)
    k_transpose_in<<<dim3(16,18,8), 256, 0, stream>>>(x5, x5t, x5tB);
    // 2. conv1x1 via bf16x3 MFMA
    k_split<0><<<256, 256, 0, stream>>>(conv_w, wAc, nullptr, 512, 65536);
    mfma_nt<0><<<dim3(4,36), 256, 0, stream>>>(wAc, x5tB, conv_b, x5t, x5r, nullptr, nullptr, 1536);
    // 3. layernorm -> xlnB (B-form, overwrites x5t region — dead)
    k_ln512b<<<NBL, 256, 0, stream>>>(x5r, ln1_g, ln1_b, xlnB);
    // 4. in_proj via MFMA
    k_split<0><<<1024, 256, 0, stream>>>(in_proj_w, wAi, nullptr, 512, 262144);
    mfma_nt<1><<<dim3(16,36), 256, 0, stream>>>(wAi, xlnB, nullptr, nullptr, xi, z, nullptr, 1536);
    // 5. depthwise conv + silu
    k_dwconv<<<dim3(4,NH,NB), 256, 0, stream>>>(xi, dwconv_w, dwconv_b, xcl);
    // 6. zero y accumulator (xi dead)
    (void)hipMemsetAsync(yacc, 0, (size_t)4718592*sizeof(float), stream);
    // 7. x_proj (fp32, small)
    gemm_nt<2><<<dim3(1,9,32), 256, 0, stream>>>(x_proj_w, xcl, nullptr, xdbl, nullptr, nullptr, 1024);
    // 8. chunked selective scan (packed fp32 inner loops)
    k_scan_p1<<<dim3(8,NCH,32), 128, 0, stream>>>(xcl, xdbl, dt_proj_w, dt_proj_b, A_logs, hfin, prodA);
    k_scan_mid<<<2048, 256, 0, stream>>>(hfin, prodA);
    k_scan_p2<<<dim3(8,NCH,32), 128, 0, stream>>>(xcl, xdbl, dt_proj_w, dt_proj_b, A_logs, hfin, yacc);
    // 9. combine + out-LN + gate -> zB directly (hfin/prodA dead)
    k_combine<<<NBL, 256, 0, stream>>>(yacc, xcl, Ds, out_norm_g, out_norm_b, z, zB);
    // 10. out_proj via MFMA (wAo in yacc region — dead)
    k_split<0><<<512, 256, 0, stream>>>(out_proj_w, wAo, nullptr, 1024, 131072);
    mfma_nt<3><<<dim3(4,36), 256, 0, stream>>>(wAo, zB, nullptr, x5r, xqf, nullptr, nullptr, 3072);
    // 11. Gram via MFMA, compact upper-tri grid (666 blocks)
    k_split<2><<<2304, 256, 0, stream>>>(xqf, xqfA, xqfB, 512, 589824);
    mfma_nt<4><<<666, 256, 0, stream>>>(xqfA, xqfB, nullptr, nullptr, nullptr, nullptr, mbuf, 1536);
    // 12. attention scalar pipeline (fused mask + tie list)
    k_mask2<<<NB, 64, 0, stream>>>(mbuf, maskf, hitcnt, hitidx);
    k_norm0<<<NBL, 256, 0, stream>>>(x5r, nrm0);
    k_seeds<<<NB, 512, 0, stream>>>(nrm0, hitcnt, hitidx, seeds);
    k_cor<<<NBL, 512, 0, stream>>>(nrm0, seeds, cor);
    k_cormap<<<NB, 64, 0, stream>>>(cor, cmap);
    k_proto<<<72, 512, 0, stream>>>(x5r, cmap, pacc);
    // 13. outputs
    k_final<<<9216, 256, 0, stream>>>(x5r, cmap, pacc, maskf, (float*)d_out);
}

// Round 11
// 607.196 us; speedup vs baseline: 1.0737x; 1.0158x over previous
//
#include <hip/hip_runtime.h>
#include <math.h>

#define NB 8
#define NC 512
#define NH 24
#define NW 24
#define NL 576        // NH*NW
#define ND 1024       // D_INNER
#define NBL 4608      // NB*NL
#define NCH 8         // scan chunks
#define CL 72         // chunk length (NL/NCH)

typedef __attribute__((ext_vector_type(8))) short bf16x8;
typedef __attribute__((ext_vector_type(4))) float f32x4;
typedef __attribute__((ext_vector_type(2))) float f32x2;

// ---------- order-preserving float<->uint encoding for atomicMax ----------
__device__ __forceinline__ unsigned enc_f(float f){
    unsigned u = __float_as_uint(f);
    return (u & 0x80000000u) ? ~u : (u | 0x80000000u);
}
__device__ __forceinline__ float dec_f(unsigned e){
    return (e & 0x80000000u) ? __uint_as_float(e ^ 0x80000000u) : __uint_as_float(~e);
}

// scan-position -> hw-index map for direction k
__device__ __forceinline__ int scan_idx(int t, int k){
    int t2 = (k >= 2) ? (NL - 1 - t) : t;
    return (k & 1) ? ((t2 % NH) * NW + t2 / NH) : t2;
}

// fast softplus / silu via v_exp/v_log
__device__ __forceinline__ float softplus_f(float x){
    return fmaxf(x, 0.f) + __logf(1.f + __expf(-fabsf(x)));
}
__device__ __forceinline__ float silu_f(float x){
    return x / (1.f + __expf(-x));
}

// fp32 -> bf16 hi/lo split (round-nearest-even both)
__device__ __forceinline__ void split_bf(float v, unsigned short &h, unsigned short &l){
    unsigned u = __float_as_uint(v);
    unsigned hr = (u + 0x7fffu + ((u>>16)&1u)) >> 16;
    h = (unsigned short)hr;
    float hf = __uint_as_float(hr << 16);
    unsigned u2 = __float_as_uint(v - hf);
    l = (unsigned short)((u2 + 0x7fffu + ((u2>>16)&1u)) >> 16);
}

// ---------- LDS-tiled transpose x5 (B,C,L) -> x5t (B,L,C) fp32 + B-form bf16 ----------
__global__ void k_transpose_in(const float* __restrict__ x5, float* __restrict__ x5t,
                               unsigned short* __restrict__ x5tB){
    __shared__ float t[32][33];
    const int b = blockIdx.z;
    const int c0 = blockIdx.x*32, l0 = blockIdx.y*32;
    const int tx = threadIdx.x & 31, ty = threadIdx.x >> 5;   // 32x8
    #pragma unroll
    for (int i=ty; i<32; i+=8)
        t[i][tx] = x5[((size_t)b*NC + c0 + i)*NL + l0 + tx];
    __syncthreads();
    #pragma unroll
    for (int i=ty; i<32; i+=8){
        float v = t[tx][i];
        x5t[((size_t)b*NL + l0 + i)*NC + c0 + tx] = v;
        unsigned short hh, ll; split_bf(v, hh, ll);
        size_t rb = ((size_t)b*NL + l0 + i)*1536 + c0 + tx;
        x5tB[rb] = hh; x5tB[rb+512] = ll; x5tB[rb+1024] = hh;
    }
}

// ---------- fp32 -> split-bf16 forms ----------
// A-form row layout (3K): [hi | hi | lo];  B-form: [hi | lo | hi]
template<int FORM>
__global__ void k_split(const float* __restrict__ in, unsigned short* __restrict__ oA,
                        unsigned short* __restrict__ oB, int K, int total4){
    int t = blockIdx.x*256 + threadIdx.x;
    if (t >= total4) return;
    int kq = K >> 2;
    int r = t / kq; int k4 = (t - r*kq) << 2;
    float4 v = *(const float4*)(in + (size_t)r*K + k4);
    float vv[4] = {v.x, v.y, v.z, v.w};
    unsigned short h[4], lo[4];
    #pragma unroll
    for (int i=0;i<4;i++) split_bf(vv[i], h[i], lo[i]);
    unsigned hp0 = h[0] | ((unsigned)h[1]<<16), hp1 = h[2] | ((unsigned)h[3]<<16);
    unsigned lp0 = lo[0] | ((unsigned)lo[1]<<16), lp1 = lo[2] | ((unsigned)lo[3]<<16);
    size_t base = (size_t)r*3*K + k4;
    if (FORM == 0 || FORM == 2){
        unsigned* p0 = (unsigned*)(oA + base);
        unsigned* p1 = (unsigned*)(oA + base + K);
        unsigned* p2 = (unsigned*)(oA + base + 2*K);
        p0[0]=hp0; p0[1]=hp1;  p1[0]=hp0; p1[1]=hp1;  p2[0]=lp0; p2[1]=lp1;
    }
    if (FORM == 1 || FORM == 2){
        unsigned short* o = (FORM==2) ? oB : oA;
        unsigned* p0 = (unsigned*)(o + base);
        unsigned* p1 = (unsigned*)(o + base + K);
        unsigned* p2 = (unsigned*)(o + base + 2*K);
        p0[0]=hp0; p0[1]=hp1;  p1[0]=lp0; p1[1]=lp1;  p2[0]=hp0; p2[1]=hp1;
    }
}

// ---------- MFMA bf16x3 NT GEMM, register-prefetch pipelined ----------
// MODE 0: conv1x1 (+bias+residual) | 1: in_proj split | 3: out_proj (+residual)
// MODE 4: gram, compact upper-tri 1D grid, row/col max -> mbuf
template<int MODE>
__launch_bounds__(256)
__global__ void mfma_nt(const unsigned short* __restrict__ A, const unsigned short* __restrict__ Bm,
                        const float* __restrict__ R0, const float* __restrict__ R1,
                        float* __restrict__ out0, float* __restrict__ out1,
                        unsigned* __restrict__ mbuf, int K3)
{
    int bi, bj;
    if (MODE == 4){
        int rem = blockIdx.x, len = 36; bi = 0;
        while (rem >= len){ rem -= len; len--; bi++; }
        bj = bi + rem;
    } else { bi = blockIdx.x; bj = blockIdx.y; }
    const int m0 = bi*128, n0 = bj*128;
    __shared__ __align__(16) unsigned short As[128*32];
    __shared__ __align__(16) unsigned short Bs[128*32];
    const int tid = threadIdx.x;
    const int w = tid >> 6, l = tid & 63;
    const int mw = (w>>1)*64, nw = (w&1)*64;
    const int fr = l & 15, fq = l >> 4;

    f32x4 acc[4][4];
    #pragma unroll
    for (int i=0;i<4;i++)
        #pragma unroll
        for (int j=0;j<4;j++)
            #pragma unroll
            for (int c=0;c<4;c++) acc[i][j][c] = 0.f;

    const int c0 = tid, c1 = tid + 256;
    const int r0 = c0 >> 2, o0 = (c0 & 3) * 8;
    const int r1 = c1 >> 2, o1 = (c1 & 3) * 8;
    const unsigned short* pA0 = A  + (size_t)(m0 + r0)*K3 + o0;
    const unsigned short* pA1 = A  + (size_t)(m0 + r1)*K3 + o1;
    const unsigned short* pB0 = Bm + (size_t)(n0 + r0)*K3 + o0;
    const unsigned short* pB1 = Bm + (size_t)(n0 + r1)*K3 + o1;

    float4 a0 = *(const float4*)(pA0);
    float4 a1 = *(const float4*)(pA1);
    float4 b0 = *(const float4*)(pB0);
    float4 b1 = *(const float4*)(pB1);

    for (int k0 = 0; k0 < K3; k0 += 32){
        __syncthreads();
        *(float4*)&As[c0*8] = a0;
        *(float4*)&As[c1*8] = a1;
        *(float4*)&Bs[c0*8] = b0;
        *(float4*)&Bs[c1*8] = b1;
        __syncthreads();
        if (k0 + 32 < K3){
            a0 = *(const float4*)(pA0 + k0 + 32);
            a1 = *(const float4*)(pA1 + k0 + 32);
            b0 = *(const float4*)(pB0 + k0 + 32);
            b1 = *(const float4*)(pB1 + k0 + 32);
        }
        bf16x8 af[4], bf[4];
        #pragma unroll
        for (int i=0;i<4;i++){
            af[i] = *(const bf16x8*)&As[(mw + i*16 + fr)*32 + fq*8];
            bf[i] = *(const bf16x8*)&Bs[(nw + i*16 + fr)*32 + fq*8];
        }
        #pragma unroll
        for (int i=0;i<4;i++)
            #pragma unroll
            for (int j=0;j<4;j++)
                acc[i][j] = __builtin_amdgcn_mfma_f32_16x16x32_bf16(af[i], bf[j], acc[i][j], 0, 0, 0);
    }

    if (MODE == 4){
        const int b2c = (n0 + nw) / NL;
        #pragma unroll
        for (int mi=0; mi<4; mi++){
            #pragma unroll
            for (int i=0;i<4;i++){
                float v = fmaxf(fmaxf(acc[mi][0][i], acc[mi][1][i]),
                                fmaxf(acc[mi][2][i], acc[mi][3][i]));
                v = fmaxf(v, __shfl_xor(v, 1));
                v = fmaxf(v, __shfl_xor(v, 2));
                v = fmaxf(v, __shfl_xor(v, 4));
                v = fmaxf(v, __shfl_xor(v, 8));
                if (fr == 0)
                    atomicMax(&mbuf[(size_t)(m0 + mw + mi*16 + fq*4 + i)*NB + b2c], enc_f(v));
            }
        }
        const int b2r = (m0 + mw) / NL;
        #pragma unroll
        for (int ni=0; ni<4; ni++){
            float cm = -3.4e38f;
            #pragma unroll
            for (int mi=0; mi<4; mi++)
                #pragma unroll
                for (int i=0;i<4;i++) cm = fmaxf(cm, acc[mi][ni][i]);
            cm = fmaxf(cm, __shfl_xor(cm, 16));
            cm = fmaxf(cm, __shfl_xor(cm, 32));
            if (fq == 0)
                atomicMax(&mbuf[(size_t)(n0 + nw + ni*16 + fr)*NB + b2r], enc_f(cm));
        }
        return;
    }

    #pragma unroll
    for (int mi=0; mi<4; mi++){
        const int m = m0 + mw + mi*16 + fq*4;
        #pragma unroll
        for (int ni=0; ni<4; ni++){
            const int n = n0 + nw + ni*16 + fr;
            f32x4 a = acc[mi][ni];
            if (MODE == 0){
                float4 cb = *(const float4*)(R0 + m);
                float4 rs = *(const float4*)(R1 + (size_t)n*NC + m);
                float4 ov = make_float4(a[0]+cb.x+rs.x, a[1]+cb.y+rs.y, a[2]+cb.z+rs.z, a[3]+cb.w+rs.w);
                *(float4*)(out0 + (size_t)n*NC + m) = ov;
            } else if (MODE == 1){
                float4 ov = make_float4(a[0], a[1], a[2], a[3]);
                if (m < ND) *(float4*)(out0 + (size_t)n*ND + m) = ov;
                else        *(float4*)(out1 + (size_t)n*ND + (m - ND)) = ov;
            } else { // MODE 3
                float4 rs = *(const float4*)(R1 + (size_t)n*NC + m);
                float4 ov = make_float4(a[0]+rs.x, a[1]+rs.y, a[2]+rs.z, a[3]+rs.w);
                *(float4*)(out0 + (size_t)n*NC + m) = ov;
            }
        }
    }
}

// ---------- fp32 NT tiled GEMM (x_proj only, MODE 2) ----------
template<int MODE>
__launch_bounds__(256)
__global__ void gemm_nt(const float* __restrict__ A0, const float* __restrict__ B0,
                        const float* __restrict__ R,
                        float* __restrict__ out0, float* __restrict__ out1,
                        unsigned* __restrict__ mbuf, int K)
{
    __shared__ __align__(16) float As[16][68];
    __shared__ __align__(16) float Bs[16][68];
    const int tid = threadIdx.x;
    const int m0 = blockIdx.x * 64;
    const int n0 = blockIdx.y * 64;
    const float* A = A0;
    const float* B = B0;
    int kdir = 0;
    if (MODE == 2) {
        const int bk = blockIdx.z;         // b*4 + k
        kdir = bk & 3; const int bb = bk >> 2;
        A = A0 + (size_t)kdir * 64 * 1024;
        B = B0 + (size_t)bb * NL * 1024;
    }
    const int lrow = tid >> 2;
    const int lk4  = (tid & 3) << 2;
    int brow = n0 + lrow;
    if (MODE == 2) brow = scan_idx(brow, kdir);
    const float* aptr = A + (size_t)(m0 + lrow) * K + lk4;
    const float* bptr = B + (size_t)brow * K + lk4;

    float acc[4][4];
    #pragma unroll
    for (int i=0;i<4;i++){
        #pragma unroll
        for (int j=0;j<4;j++) acc[i][j]=0.f;
    }
    const int tx = tid & 15, ty = tid >> 4;

    for (int k0 = 0; k0 < K; k0 += 16) {
        float4 av = *(const float4*)(aptr + k0);
        float4 bv = *(const float4*)(bptr + k0);
        __syncthreads();
        As[lk4+0][lrow]=av.x; As[lk4+1][lrow]=av.y; As[lk4+2][lrow]=av.z; As[lk4+3][lrow]=av.w;
        Bs[lk4+0][lrow]=bv.x; Bs[lk4+1][lrow]=bv.y; Bs[lk4+2][lrow]=bv.z; Bs[lk4+3][lrow]=bv.w;
        __syncthreads();
        #pragma unroll
        for (int kk=0;kk<16;kk++){
            float4 a = *(const float4*)&As[kk][ty<<2];
            float4 b = *(const float4*)&Bs[kk][tx<<2];
            acc[0][0] = fmaf(a.x,b.x,acc[0][0]); acc[0][1] = fmaf(a.x,b.y,acc[0][1]);
            acc[0][2] = fmaf(a.x,b.z,acc[0][2]); acc[0][3] = fmaf(a.x,b.w,acc[0][3]);
            acc[1][0] = fmaf(a.y,b.x,acc[1][0]); acc[1][1] = fmaf(a.y,b.y,acc[1][1]);
            acc[1][2] = fmaf(a.y,b.z,acc[1][2]); acc[1][3] = fmaf(a.y,b.w,acc[1][3]);
            acc[2][0] = fmaf(a.z,b.x,acc[2][0]); acc[2][1] = fmaf(a.z,b.y,acc[2][1]);
            acc[2][2] = fmaf(a.z,b.z,acc[2][2]); acc[2][3] = fmaf(a.z,b.w,acc[2][3]);
            acc[3][0] = fmaf(a.w,b.x,acc[3][0]); acc[3][1] = fmaf(a.w,b.y,acc[3][1]);
            acc[3][2] = fmaf(a.w,b.z,acc[3][2]); acc[3][3] = fmaf(a.w,b.w,acc[3][3]);
        }
    }

    #pragma unroll
    for (int j=0;j<4;j++){
        const int n  = n0 + (tx<<2) + j;
        const int mm = m0 + (ty<<2);
        float4 v = make_float4(acc[0][j], acc[1][j], acc[2][j], acc[3][j]);
        if (MODE == 2){
            *(float4*)(out0 + ((size_t)blockIdx.z*NL + n)*64 + mm) = v;
        }
    }
}

// ---------- layernorm over C=512, directly to B-form bf16x3 ----------
__global__ void k_ln512b(const float* __restrict__ x, const float* __restrict__ g,
                         const float* __restrict__ bb, unsigned short* __restrict__ outB){
    int n = blockIdx.x; int tid = threadIdx.x;     // 256 threads
    const float* row = x + (size_t)n*NC;
    float v0 = row[tid], v1 = row[tid+256];
    __shared__ float s1[256], s2[256];
    s1[tid] = v0+v1; s2[tid] = v0*v0 + v1*v1;
    __syncthreads();
    for (int s=128;s>0;s>>=1){ if (tid<s){ s1[tid]+=s1[tid+s]; s2[tid]+=s2[tid+s]; } __syncthreads(); }
    float mean = s1[0]*(1.f/NC);
    float var  = fmaxf(s2[0]*(1.f/NC) - mean*mean, 0.f);
    float rs   = rsqrtf(var + 1e-5f);
    float r0 = (v0-mean)*rs*g[tid]     + bb[tid];
    float r1 = (v1-mean)*rs*g[tid+256] + bb[tid+256];
    unsigned short h0,l0,h1,l1; split_bf(r0,h0,l0); split_bf(r1,h1,l1);
    size_t base = (size_t)n*1536;
    outB[base+tid]     =h0; outB[base+512+tid]     =l0; outB[base+1024+tid]     =h0;
    outB[base+tid+256] =h1; outB[base+512+tid+256] =l1; outB[base+1024+tid+256] =h1;
}

// ---------- depthwise 3x3 SAME + bias + SiLU, rolling window ----------
__global__ void k_dwconv(const float* __restrict__ xi, const float* __restrict__ w,
                         const float* __restrict__ bias, float* __restrict__ xcl){
    int d = blockIdx.x*256 + threadIdx.x;          // 0..1023
    int h = blockIdx.y; int b = blockIdx.z;
    float W[9];
    #pragma unroll
    for (int i=0;i<9;i++) W[i] = w[d*9+i];
    float bs = bias[d];
    const size_t rb = ((size_t)b*NL)*ND + d;
    const bool hm = h > 0, hp = h < NH-1;
    float p0=0.f,p1=0.f,p2=0.f;
    float c0 = hm ? xi[rb + (size_t)((h-1)*NW)*ND] : 0.f;
    float c1 = xi[rb + (size_t)(h*NW)*ND];
    float c2 = hp ? xi[rb + (size_t)((h+1)*NW)*ND] : 0.f;
    for (int wc=0; wc<NW; wc++){
        float n0,n1,n2;
        if (wc < NW-1){
            n0 = hm ? xi[rb + (size_t)((h-1)*NW+wc+1)*ND] : 0.f;
            n1 = xi[rb + (size_t)(h*NW+wc+1)*ND];
            n2 = hp ? xi[rb + (size_t)((h+1)*NW+wc+1)*ND] : 0.f;
        } else { n0=0.f;n1=0.f;n2=0.f; }
        float acc = bs;
        acc = fmaf(W[0],p0, fmaf(W[1],c0, fmaf(W[2],n0, acc)));
        acc = fmaf(W[3],p1, fmaf(W[4],c1, fmaf(W[5],n1, acc)));
        acc = fmaf(W[6],p2, fmaf(W[7],c2, fmaf(W[8],n2, acc)));
        xcl[rb + (size_t)(h*NW+wc)*ND] = silu_f(acc);
        p0=c0;p1=c1;p2=c2; c0=n0;c1=n1;c2=n2;
    }
}

// packed dA power tree from e1 -> f32x2 dA2[8], pairs (2n,2n+1)
#define DA_POWERS2 \
    float e2=e1*e1; float e3=e2*e1; float e4=e2*e2; \
    float e6=e4*e2; float e7=e4*e3; float e8=e4*e4; float e12=e8*e4; \
    f32x2 dA2[8]; \
    dA2[0]=(f32x2){e1,e2};       dA2[1]=(f32x2){e3,e4}; \
    dA2[2]=(f32x2){e4*e1,e6};    dA2[3]=(f32x2){e7,e8}; \
    dA2[4]=(f32x2){e8*e1,e8*e2}; dA2[5]=(f32x2){e8*e3,e12}; \
    dA2[6]=(f32x2){e12*e1,e12*e2}; dA2[7]=(f32x2){e12*e3,e8*e8};

// packed dot via float4 register loads (16x ds_read_b128 total incl. B/C)
#define DOTP_F4(rq4, dtb, out) { \
    f32x2 sA={0.f,0.f}, sB={0.f,0.f}; \
    _Pragma("unroll") \
    for (int i_=0;i_<8;i_++){ \
        float4 qq = rq4[i_]; \
        f32x2 lo; lo.x=qq.x; lo.y=qq.y; \
        f32x2 hi; hi.x=qq.z; hi.y=qq.w; \
        if (i_ & 1){ sB += lo*wdt2[2*i_]; sB += hi*wdt2[2*i_+1]; } \
        else       { sA += lo*wdt2[2*i_]; sA += hi*wdt2[2*i_+1]; } \
    } \
    out = (sA.x+sA.y)+(sB.x+sB.y)+dtb; }

// ---------- chunked selective scan, pass 1 (128 threads, packed fp32) ----------
__launch_bounds__(128)
__global__ void k_scan_p1(const float* __restrict__ xcl, const float* __restrict__ xdbl,
                          const float* __restrict__ dtw, const float* __restrict__ dtb,
                          const float* __restrict__ alogs,
                          float* __restrict__ hfin, float* __restrict__ prodA){
    const int d = blockIdx.x*128 + threadIdx.x;
    const int chunk = blockIdx.y;
    const int bk = blockIdx.z;
    const int k = bk & 3, b = bk >> 2;
    const int kd = k*ND + d;
    f32x2 wdt2[16];
    {
        const float4* p = (const float4*)(dtw + (size_t)kd*32);
        #pragma unroll
        for (int i=0;i<8;i++){
            float4 v=p[i];
            wdt2[2*i]   = (f32x2){v.x, v.y};
            wdt2[2*i+1] = (f32x2){v.z, v.w};
        }
    }
    float An[16]; bool ladder = true;
    {
        const float4* p = (const float4*)(alogs + (size_t)kd*16);
        #pragma unroll
        for (int i=0;i<4;i++){
            float4 v=p[i];
            An[4*i]=-__expf(v.x); An[4*i+1]=-__expf(v.y); An[4*i+2]=-__expf(v.z); An[4*i+3]=-__expf(v.w);
        }
        #pragma unroll
        for (int n=0;n<16;n++) ladder = ladder && (fabsf(An[n] + (float)(n+1)) < 1e-3f*(n+1));
    }
    const float dtbias = dtb[kd];
    __shared__ __align__(16) float rows[CL*64];
    {
        const float4* src = (const float4*)(xdbl + ((size_t)bk*NL + chunk*CL)*64);
        for (int i = threadIdx.x; i < CL*16; i += 128) ((float4*)rows)[i] = src[i];
    }
    __syncthreads();
    if (ladder){
        f32x2 h2[8], pA2[8];
        #pragma unroll
        for (int n=0;n<8;n++){ h2[n]=(f32x2){0.f,0.f}; pA2[n]=(f32x2){1.f,1.f}; }
        float u = xcl[((size_t)b*NL + scan_idx(chunk*CL, k))*ND + d];
        for (int t=0;t<CL;t++){
            const float4* rq4 = (const float4*)(rows + t*64);
            float dr; DOTP_F4(rq4, dtbias, dr);
            float u_cur = u;
            if (t+1 < CL) u = xcl[((size_t)b*NL + scan_idx(chunk*CL+t+1, k))*ND + d];
            float sp = softplus_f(dr);
            float du = sp * u_cur;
            float e1 = __expf(-sp);
            DA_POWERS2
            float4 qB[4];
            #pragma unroll
            for (int i=0;i<4;i++) qB[i] = rq4[8+i];
            f32x2 Bv[8];
            #pragma unroll
            for (int i=0;i<4;i++){
                Bv[2*i].x=qB[i].x; Bv[2*i].y=qB[i].y;
                Bv[2*i+1].x=qB[i].z; Bv[2*i+1].y=qB[i].w;
            }
            f32x2 du2 = (f32x2){du, du};
            #pragma unroll
            for (int n=0;n<8;n++){
                pA2[n] *= dA2[n];
                h2[n] = dA2[n]*h2[n] + du2*Bv[n];
            }
        }
        size_t base = (size_t)(bk*NCH + chunk)*16*1024 + d;
        #pragma unroll
        for (int n=0;n<8;n++){
            hfin[base + (2*n)*1024]   = h2[n].x;  hfin[base + (2*n+1)*1024] = h2[n].y;
            prodA[base + (2*n)*1024]  = pA2[n].x; prodA[base + (2*n+1)*1024]= pA2[n].y;
        }
    } else {
        float h[16], pA[16];
        #pragma unroll
        for (int n=0;n<16;n++){ h[n]=0.f; pA[n]=1.f; }
        for (int t=0;t<CL;t++){
            const float4* rq4 = (const float4*)(rows + t*64);
            float dr; DOTP_F4(rq4, dtbias, dr);
            float sp = softplus_f(dr);
            int idx = scan_idx(chunk*CL + t, k);
            float u  = xcl[((size_t)b*NL + idx)*ND + d];
            float du = sp * u;
            const float* row = rows + t*64;
            #pragma unroll
            for (int n=0;n<16;n++){
                float dA = __expf(sp * An[n]);
                pA[n] *= dA;
                h[n] = fmaf(dA, h[n], du*row[32+n]);
            }
        }
        size_t base = (size_t)(bk*NCH + chunk)*16*1024 + d;
        #pragma unroll
        for (int n=0;n<16;n++){ hfin[base + n*1024] = h[n]; prodA[base + n*1024] = pA[n]; }
    }
}

// ---------- chunked scan, mid ----------
__global__ void k_scan_mid(float* __restrict__ hfin, const float* __restrict__ prodA){
    int id = blockIdx.x*256 + threadIdx.x;
    int d = id & 1023, nn = (id >> 10) & 15, bk = id >> 14;
    float h = 0.f;
    for (int j=0;j<NCH;j++){
        size_t idx = (size_t)((bk*NCH + j)*16 + nn)*1024 + d;
        float hf = hfin[idx], pa = prodA[idx];
        hfin[idx] = h;
        h = fmaf(pa, h, hf);
    }
}

// ---------- chunked scan, pass 2 (128 threads, packed fp32) ----------
__launch_bounds__(128)
__global__ void k_scan_p2(const float* __restrict__ xcl, const float* __restrict__ xdbl,
                          const float* __restrict__ dtw, const float* __restrict__ dtb,
                          const float* __restrict__ alogs,
                          const float* __restrict__ hfin, float* __restrict__ yacc){
    const int d = blockIdx.x*128 + threadIdx.x;
    const int chunk = blockIdx.y;
    const int bk = blockIdx.z;
    const int k = bk & 3, b = bk >> 2;
    const int kd = k*ND + d;
    f32x2 wdt2[16];
    {
        const float4* p = (const float4*)(dtw + (size_t)kd*32);
        #pragma unroll
        for (int i=0;i<8;i++){
            float4 v=p[i];
            wdt2[2*i]   = (f32x2){v.x, v.y};
            wdt2[2*i+1] = (f32x2){v.z, v.w};
        }
    }
    float An[16]; bool ladder = true;
    {
        const float4* p = (const float4*)(alogs + (size_t)kd*16);
        #pragma unroll
        for (int i=0;i<4;i++){
            float4 v=p[i];
            An[4*i]=-__expf(v.x); An[4*i+1]=-__expf(v.y); An[4*i+2]=-__expf(v.z); An[4*i+3]=-__expf(v.w);
        }
        #pragma unroll
        for (int n=0;n<16;n++) ladder = ladder && (fabsf(An[n] + (float)(n+1)) < 1e-3f*(n+1));
    }
    const float dtbias = dtb[kd];
    __shared__ __align__(16) float rows[CL*64];
    {
        const float4* src = (const float4*)(xdbl + ((size_t)bk*NL + chunk*CL)*64);
        for (int i = threadIdx.x; i < CL*16; i += 128) ((float4*)rows)[i] = src[i];
    }
    __syncthreads();
    if (ladder){
        f32x2 h2[8];
        {
            size_t base = (size_t)(bk*NCH + chunk)*16*1024 + d;
            #pragma unroll
            for (int n=0;n<8;n++)
                h2[n] = (f32x2){hfin[base + (2*n)*1024], hfin[base + (2*n+1)*1024]};
        }
        int idx = scan_idx(chunk*CL, k);
        float u = xcl[((size_t)b*NL + idx)*ND + d];
        for (int t=0;t<CL;t++){
            const float4* rq4 = (const float4*)(rows + t*64);
            float dr; DOTP_F4(rq4, dtbias, dr);
            float u_cur = u; int idx_cur = idx;
            if (t+1 < CL){
                idx = scan_idx(chunk*CL+t+1, k);
                u = xcl[((size_t)b*NL + idx)*ND + d];
            }
            float sp = softplus_f(dr);
            float du = sp * u_cur;
            float e1 = __expf(-sp);
            DA_POWERS2
            float4 qB[4], qC[4];
            #pragma unroll
            for (int i=0;i<4;i++){ qB[i] = rq4[8+i]; qC[i] = rq4[12+i]; }
            f32x2 Bv[8], Cv[8];
            #pragma unroll
            for (int i=0;i<4;i++){
                Bv[2*i].x=qB[i].x; Bv[2*i].y=qB[i].y;
                Bv[2*i+1].x=qB[i].z; Bv[2*i+1].y=qB[i].w;
                Cv[2*i].x=qC[i].x; Cv[2*i].y=qC[i].y;
                Cv[2*i+1].x=qC[i].z; Cv[2*i+1].y=qC[i].w;
            }
            f32x2 du2 = (f32x2){du, du};
            f32x2 y2 = (f32x2){0.f, 0.f};
            #pragma unroll
            for (int n=0;n<8;n++){
                h2[n] = dA2[n]*h2[n] + du2*Bv[n];
                y2 += h2[n]*Cv[n];
            }
            atomicAdd(&yacc[((size_t)b*NL + idx_cur)*ND + d], y2.x + y2.y);
        }
    } else {
        float h[16];
        {
            size_t base = (size_t)(bk*NCH + chunk)*16*1024 + d;
            #pragma unroll
            for (int n=0;n<16;n++) h[n] = hfin[base + n*1024];
        }
        for (int t=0;t<CL;t++){
            const float4* rq4 = (const float4*)(rows + t*64);
            float dr; DOTP_F4(rq4, dtbias, dr);
            float sp = softplus_f(dr);
            int idx = scan_idx(chunk*CL + t, k);
            size_t base = ((size_t)b*NL + idx)*ND + d;
            float u  = xcl[base];
            float du = sp * u;
            const float* row = rows + t*64;
            float y = 0.f;
            #pragma unroll
            for (int n=0;n<16;n++){
                float dA = __expf(sp * An[n]);
                h[n] = fmaf(dA, h[n], du*row[32+n]);
                y = fmaf(h[n], row[48+n], y);
            }
            atomicAdd(&yacc[base], y);
        }
    }
}

// ---------- combine y + Ds*u, LN over D, gate with silu(z) -> zB (B-form bf16x3) ----------
__global__ void k_combine(const float* __restrict__ y, const float* __restrict__ xcl,
                          const float* __restrict__ Ds,
                          const float* __restrict__ g, const float* __restrict__ bb,
                          const float* __restrict__ z, unsigned short* __restrict__ zB){
    int n = blockIdx.x;
    size_t base = (size_t)n*ND;
    int tid = threadIdx.x;
    float v[4]; float sum=0.f, sq=0.f;
    #pragma unroll
    for (int j=0;j<4;j++){
        int d = tid + 256*j;
        float ds = Ds[d] + Ds[ND+d] + Ds[2*ND+d] + Ds[3*ND+d];
        float val = y[base+d] + ds*xcl[base+d];
        v[j]=val; sum+=val; sq+=val*val;
    }
    __shared__ float s1[256], s2[256];
    s1[tid]=sum; s2[tid]=sq; __syncthreads();
    for (int st=128;st>0;st>>=1){ if(tid<st){ s1[tid]+=s1[tid+st]; s2[tid]+=s2[tid+st]; } __syncthreads(); }
    float mean = s1[0]*(1.f/ND);
    float var  = fmaxf(s2[0]*(1.f/ND) - mean*mean, 0.f);
    float rs   = rsqrtf(var + 1e-5f);
    size_t zb = (size_t)n*3072;
    #pragma unroll
    for (int j=0;j<4;j++){
        int d = tid + 256*j;
        float ln = (v[j]-mean)*rs*g[d] + bb[d];
        float res = ln * silu_f(z[base+d]);
        unsigned short hh,ll; split_bf(res,hh,ll);
        zB[zb + d] = hh; zB[zb + 1024 + d] = ll; zB[zb + 2048 + d] = hh;
    }
}

// ---------- fused xwpre + argmax mask + tie list (one wave per b) ----------
__global__ void k_mask2(const unsigned* __restrict__ M, float* __restrict__ maskf,
                        int* __restrict__ hitcnt, int* __restrict__ hitidx){
    int b = blockIdx.x; int tid = threadIdx.x;     // 64 threads
    __shared__ int lcnt;
    if (tid == 0) lcnt = 0;
    __syncthreads();
    float loc[9];
    float m = -3.4e38f;
    #pragma unroll
    for (int j=0;j<9;j++){
        int l = tid + j*64;
        float s = 0.f;
        #pragma unroll
        for (int b2=0;b2<NB;b2++) s += dec_f(M[(size_t)(b*NL+l)*NB + b2]);
        loc[j] = s; m = fmaxf(m, s);
    }
    #pragma unroll
    for (int s=32;s>0;s>>=1) m = fmaxf(m, __shfl_xor(m, s));
    #pragma unroll
    for (int j=0;j<9;j++){
        int l = tid + j*64;
        bool hit = (loc[j] == m);
        maskf[b*NL + l] = hit ? 1.f : 0.f;
        if (hit){
            int pos = atomicAdd(&lcnt, 1);
            hitidx[b*NL + pos] = l;
        }
    }
    __syncthreads();
    if (tid == 0) hitcnt[b] = lcnt;
}

// ---------- channel-norm: norm0 (B,L,C) ----------
__global__ void k_norm0(const float* __restrict__ x5r, float* __restrict__ norm0){
    int n = blockIdx.x; int tid = threadIdx.x;     // 256
    float v0 = x5r[(size_t)n*NC+tid], v1 = x5r[(size_t)n*NC+tid+256];
    __shared__ float s1[256];
    s1[tid] = v0*v0 + v1*v1; __syncthreads();
    for (int st=128;st>0;st>>=1){ if(tid<st) s1[tid]+=s1[tid+st]; __syncthreads(); }
    float inv = 1.f / fmaxf(sqrtf(s1[0]), 1e-12f);
    norm0[(size_t)n*NC+tid]     = v0*inv;
    norm0[(size_t)n*NC+tid+256] = v1*inv;
}

// ---------- seeds[b,c] = sum over tie-list rows of norm0 ----------
__global__ void k_seeds(const float* __restrict__ norm0, const int* __restrict__ hitcnt,
                        const int* __restrict__ hitidx, float* __restrict__ seeds){
    int b = blockIdx.x; int c = threadIdx.x;       // 512
    int cnt = hitcnt[b];
    float acc = 0.f;
    for (int i=0;i<cnt;i++){
        int l = hitidx[b*NL + i];
        acc += norm0[((size_t)b*NL+l)*NC + c];
    }
    seeds[b*NC + c] = acc;
}

// ---------- cor[b,l] = mean_o relu(norm0 . seeds_o), wave-per-o ----------
__global__ void k_cor(const float* __restrict__ norm0, const float* __restrict__ seeds,
                      float* __restrict__ cor){
    int n = blockIdx.x; int tid = threadIdx.x;     // 512 = 8 waves
    int o = tid >> 6, lane = tid & 63;
    float acc = 0.f;
    #pragma unroll
    for (int i=0;i<8;i++){
        int c = lane + 64*i;
        acc += norm0[(size_t)n*NC + c] * seeds[o*NC + c];
    }
    #pragma unroll
    for (int s=32;s>0;s>>=1) acc += __shfl_xor(acc, s);
    __shared__ float sr[8];
    if (lane == 0) sr[o] = fmaxf(acc, 0.f);
    __syncthreads();
    if (tid == 0){
        float r = 0.f;
        #pragma unroll
        for (int o2=0;o2<8;o2++) r += sr[o2];
        cor[n] = r * (1.f/8.f);
    }
}

// ---------- cormap per b ----------
__global__ void k_cormap(const float* __restrict__ cor, float* __restrict__ cmap){
    int b = blockIdx.x, tid = threadIdx.x;         // 64
    float mn = 1e30f, mx = -1e30f;
    for (int i=tid;i<NL;i+=64){ float v=cor[b*NL+i]; mn=fminf(mn,v); mx=fmaxf(mx,v); }
    __shared__ float sn[64], sx[64];
    sn[tid]=mn; sx[tid]=mx; __syncthreads();
    for (int st=32;st>0;st>>=1){ if(tid<st){ sn[tid]=fminf(sn[tid],sn[tid+st]); sx[tid]=fmaxf(sx[tid],sx[tid+st]); } __syncthreads(); }
    float MN=sn[0], MX=sx[0];
    float inv = 1.f/(MX-MN+1e-12f);
    for (int i=tid;i<NL;i+=64) cmap[b*NL+i] = (cor[b*NL+i]-MN)*inv;
}

// ---------- proto accumulation ----------
__global__ void k_proto(const float* __restrict__ x5r, const float* __restrict__ cmap,
                        float* __restrict__ pacc){
    int c = threadIdx.x;                            // 512
    int chunk = blockIdx.x;                         // 72 chunks of 64
    float acc = 0.f;
    for (int i=0;i<64;i++){
        int n = chunk*64 + i;
        acc += x5r[(size_t)n*NC + c] * cmap[n];
    }
    atomicAdd(&pacc[c], acc);
}

// ---------- final outputs 0 & 2, LDS-tiled transpose (mirrors k_transpose_in) ----------
__global__ void k_final_t(const float* __restrict__ x5r, const float* __restrict__ cmap,
                          const float* __restrict__ pacc, float* __restrict__ out){
    __shared__ float t[32][33];
    const int b = blockIdx.z;
    const int c0 = blockIdx.x*32, l0 = blockIdx.y*32;
    const int tx = threadIdx.x & 31, ty = threadIdx.x >> 5;   // 32x8
    #pragma unroll
    for (int i=ty; i<32; i+=8)
        t[i][tx] = x5r[((size_t)b*NL + l0 + i)*NC + c0 + tx];
    __syncthreads();
    #pragma unroll
    for (int i=ty; i<32; i+=8){
        float v = t[tx][i];
        int c = c0 + i, l = l0 + tx;
        size_t o = ((size_t)b*NC + c)*NL + l;
        out[o] = v;
        out[2359808 + o] = v*(pacc[c]*(1.f/(float)NBL) + cmap[b*NL + l]);
    }
}

// ---------- final small outputs (1: proto, 3: mask) ----------
__global__ void k_final_s(const float* __restrict__ pacc, const float* __restrict__ maskf,
                          float* __restrict__ out){
    int id = blockIdx.x*256 + threadIdx.x;          // 5120
    if (id < 512) out[2359296 + id] = pacc[id]*(1.f/(float)NBL);
    int j = id - 512;
    if (j >= 0 && j < NBL) out[2359808 + 2359296 + j] = maskf[j];
}

// ---------------- launcher ----------------
extern "C" void kernel_launch(void* const* d_in, const int* in_sizes, int n_in,
                              void* d_out, int out_size, void* d_ws, size_t ws_size,
                              hipStream_t stream) {
    const float* x5        = (const float*)d_in[0];
    const float* conv_w    = (const float*)d_in[1];
    const float* conv_b    = (const float*)d_in[2];
    const float* ln1_g     = (const float*)d_in[3];
    const float* ln1_b     = (const float*)d_in[4];
    const float* in_proj_w = (const float*)d_in[5];
    const float* dwconv_w  = (const float*)d_in[6];
    const float* dwconv_b  = (const float*)d_in[7];
    const float* x_proj_w  = (const float*)d_in[8];
    const float* dt_proj_w = (const float*)d_in[9];
    const float* dt_proj_b = (const float*)d_in[10];
    const float* A_logs    = (const float*)d_in[11];
    const float* Ds        = (const float*)d_in[12];
    const float* out_norm_g= (const float*)d_in[13];
    const float* out_norm_b= (const float*)d_in[14];
    const float* out_proj_w= (const float*)d_in[15];

    float* ws = (float*)d_ws;
    const size_t O_X5R  = 0;          // x5r (permanent)
    const size_t O_XLN  = 2359296;    // xqf
    const size_t O_XI   = 4718592;    // xi -> yacc -> wAo
    const size_t O_Z    = 9437184;    // z
    const size_t O_XCL  = 14155776;   // wAi -> xcl -> nrm0
    const size_t O_XDBL = 18874368;   // xdbl
    const size_t O_HF   = 20054016;   // x5t -> xlnB -> hfin -> zB(span) -> xqfA
    const size_t O_PA   = 24248320;   // x5tB+wAc -> prodA -> zB(tail) -> xqfB
    const size_t O_MBUF = 28442624;
    const size_t O_MASK = 28484096;
    const size_t O_COR  = 28488704;
    const size_t O_CMAP = 28493312;
    const size_t O_SEED = 28497920;
    const size_t O_PACC = 28502016;
    const size_t O_HITC = 28502528;   // 8 ints
    const size_t O_HITI = 28502544;   // 4608 ints

    float* x5r  = ws + O_X5R;
    float* xqf  = ws + O_XLN;
    float* xi   = ws + O_XI;
    float* yacc = ws + O_XI;
    unsigned short* wAo = (unsigned short*)(ws + O_XI);
    float* z    = ws + O_Z;
    float* xcl  = ws + O_XCL;
    unsigned short* wAi = (unsigned short*)(ws + O_XCL);
    float* nrm0 = ws + O_XCL;
    float* xdbl = ws + O_XDBL;
    float* x5t  = ws + O_HF;
    float* hfin = ws + O_HF;
    unsigned short* xlnB = (unsigned short*)(ws + O_HF);
    unsigned short* zB   = (unsigned short*)(ws + O_HF);
    unsigned short* xqfA = (unsigned short*)(ws + O_HF);
    float* prodA = ws + O_PA;
    unsigned short* x5tB = (unsigned short*)(ws + O_PA);
    unsigned short* wAc  = (unsigned short*)(ws + O_PA) + 7077888;
    unsigned short* xqfB = (unsigned short*)(ws + O_PA);
    unsigned* mbuf = (unsigned*)(ws + O_MBUF);
    float* maskf= ws + O_MASK;
    float* cor  = ws + O_COR;
    float* cmap = ws + O_CMAP;
    float* seeds= ws + O_SEED;
    float* pacc = ws + O_PACC;
    int* hitcnt = (int*)(ws + O_HITC);
    int* hitidx = (int*)(ws + O_HITI);

    (void)hipMemsetAsync(mbuf, 0, 36864*sizeof(unsigned), stream);
    (void)hipMemsetAsync(pacc, 0, 512*sizeof(float), stream);

    // 1. transpose x5 -> x5t (fp32) + x5tB (B-form bf16x3)
    k_transpose_in<<<dim3(16,18,8), 256, 0, stream>>>(x5, x5t, x5tB);
    // 2. conv1x1 via bf16x3 MFMA
    k_split<0><<<256, 256, 0, stream>>>(conv_w, wAc, nullptr, 512, 65536);
    mfma_nt<0><<<dim3(4,36), 256, 0, stream>>>(wAc, x5tB, conv_b, x5t, x5r, nullptr, nullptr, 1536);
    // 3. layernorm -> xlnB (B-form, overwrites x5t region — dead)
    k_ln512b<<<NBL, 256, 0, stream>>>(x5r, ln1_g, ln1_b, xlnB);
    // 4. in_proj via MFMA
    k_split<0><<<1024, 256, 0, stream>>>(in_proj_w, wAi, nullptr, 512, 262144);
    mfma_nt<1><<<dim3(16,36), 256, 0, stream>>>(wAi, xlnB, nullptr, nullptr, xi, z, nullptr, 1536);
    // 5. depthwise conv + silu
    k_dwconv<<<dim3(4,NH,NB), 256, 0, stream>>>(xi, dwconv_w, dwconv_b, xcl);
    // 6. zero y accumulator (xi dead)
    (void)hipMemsetAsync(yacc, 0, (size_t)4718592*sizeof(float), stream);
    // 7. x_proj (fp32, small)
    gemm_nt<2><<<dim3(1,9,32), 256, 0, stream>>>(x_proj_w, xcl, nullptr, xdbl, nullptr, nullptr, 1024);
    // 8. chunked selective scan (packed fp32 math, float4 LDS loads)
    k_scan_p1<<<dim3(8,NCH,32), 128, 0, stream>>>(xcl, xdbl, dt_proj_w, dt_proj_b, A_logs, hfin, prodA);
    k_scan_mid<<<2048, 256, 0, stream>>>(hfin, prodA);
    k_scan_p2<<<dim3(8,NCH,32), 128, 0, stream>>>(xcl, xdbl, dt_proj_w, dt_proj_b, A_logs, hfin, yacc);
    // 9. combine + out-LN + gate -> zB directly (hfin/prodA dead)
    k_combine<<<NBL, 256, 0, stream>>>(yacc, xcl, Ds, out_norm_g, out_norm_b, z, zB);
    // 10. out_proj via MFMA (wAo in yacc region — dead)
    k_split<0><<<512, 256, 0, stream>>>(out_proj_w, wAo, nullptr, 1024, 131072);
    mfma_nt<3><<<dim3(4,36), 256, 0, stream>>>(wAo, zB, nullptr, x5r, xqf, nullptr, nullptr, 3072);
    // 11. Gram via MFMA, compact upper-tri grid (666 blocks)
    k_split<2><<<2304, 256, 0, stream>>>(xqf, xqfA, xqfB, 512, 589824);
    mfma_nt<4><<<666, 256, 0, stream>>>(xqfA, xqfB, nullptr, nullptr, nullptr, nullptr, mbuf, 1536);
    // 12. attention scalar pipeline (fused mask + tie list)
    k_mask2<<<NB, 64, 0, stream>>>(mbuf, maskf, hitcnt, hitidx);
    k_norm0<<<NBL, 256, 0, stream>>>(x5r, nrm0);
    k_seeds<<<NB, 512, 0, stream>>>(nrm0, hitcnt, hitidx, seeds);
    k_cor<<<NBL, 512, 0, stream>>>(nrm0, seeds, cor);
    k_cormap<<<NB, 64, 0, stream>>>(cor, cmap);
    k_proto<<<72, 512, 0, stream>>>(x5r, cmap, pacc);
    // 13. outputs (LDS-tiled transpose + small tail)
    k_final_t<<<dim3(16,18,8), 256, 0, stream>>>(x5r, cmap, pacc, (float*)d_out);
    k_final_s<<<20, 256, 0, stream>>>(pacc, maskf, (float*)d_out);
}